// Round 17
// baseline (1076.413 us; speedup 1.0000x reference)
//
#include <hip/hip_runtime.h>
#include <hip/hip_bf16.h>

// ---------------------------------------------------------------------------
// MLDecoder forward on MI355X (gfx950).  Round 17:
//  - GEMM template gains f32 operand modes: AM1 (A f32 row-major), BM1 (B f32
//    BT), BM2 (B f32 [K,N], transpose-in-LDS with pad-66 leading dim -> b128
//    fragment reads conflict-free, ~8-way scalar ds_write on tiny GEMMs).
//  - Combine GEMMs read Wk_c/Wq_c/Wv_c f32 directly (CQ/CK/CV casts GONE);
//    qkv + o_s GEMMs read Wq_s/Wk_s/Wv_s/Wo_s f32 [K,N] directly (the four
//    s-weight transposes GONE).  prep grid 29,028 -> 10,596 blocks.
//  - Everything else identical to round 16.
// ---------------------------------------------------------------------------

typedef __attribute__((ext_vector_type(8))) short short8;   // 8 bf16
typedef __attribute__((ext_vector_type(4))) short short4b;  // 4 bf16
typedef __attribute__((ext_vector_type(4))) float floatx4;

#define DEVI static __device__ __forceinline__

DEVI short f2bf(float f) {
    union { __hip_bfloat16 h; short s; } u;
    u.h = __float2bfloat16(f);
    return u.s;
}

DEVI float bf2f(short s) {
    union { float f; unsigned u; } v;
    v.u = ((unsigned)(unsigned short)s) << 16;
    return v.f;
}

DEVI void gld_lds16(const void* g, void* l) {
    __builtin_amdgcn_global_load_lds(
        (const __attribute__((address_space(1))) void*)g,
        (__attribute__((address_space(3))) void*)l, 16, 0, 0);
}

// ---------------------------------------------------------------------------
// prep_kernel: input-only prep in one launch.
//   blocks [0,384)       W_embed [2048x768] -> WembT (ld 2048)
//   blocks [384,768)     W1      [768x2048] -> W1T   (ld 768)
//   blocks [768,1152)    W2      [2048x768] -> W2T   (ld 2048)
//   blocks [1152,2304)   Wo_c    [6144x768] -> WoTc  (ld 6144)
//   blocks [2304,10496)  x [64][2048][196]  -> xT [64][196][2048] bf16
//   blocks [10496,10596) LN1(query_embed)   -> hn1 (100 rows)
// ---------------------------------------------------------------------------
__global__ __launch_bounds__(256)
void prep_kernel(const float* __restrict__ W_embed, const float* __restrict__ W1,
                 const float* __restrict__ W2, const float* __restrict__ Wo_c,
                 const float* __restrict__ x,
                 const float* __restrict__ qe, const float* __restrict__ ln1_g,
                 const float* __restrict__ ln1_b,
                 short* __restrict__ WembT, short* __restrict__ W1T,
                 short* __restrict__ W2T, short* __restrict__ WoTc,
                 short* __restrict__ xT, short* __restrict__ hn1)
{
    const int bid = blockIdx.x;
    const int t = threadIdx.x;

    __shared__ __align__(16) short tile[64][65];

    // ---------------- LN1 job ----------------
    if (bid >= 10496) {
        const int row = bid - 10496;
        float* ss  = (float*)&tile[0][0];
        float* ssq = ss + 4;
        float4 v = {0.f, 0.f, 0.f, 0.f};
        float s = 0.f, sq = 0.f;
        if (t < 192) {
            v = *(const float4*)(qe + (long)row * 768 + (t << 2));
            s  = v.x + v.y + v.z + v.w;
            sq = v.x * v.x + v.y * v.y + v.z * v.z + v.w * v.w;
            #pragma unroll
            for (int off = 32; off; off >>= 1) {
                s  += __shfl_xor(s, off);
                sq += __shfl_xor(sq, off);
            }
            if ((t & 63) == 0) { ss[t >> 6] = s; ssq[t >> 6] = sq; }
        }
        __syncthreads();
        if (t < 192) {
            s  = ss[0] + ss[1] + ss[2];
            sq = ssq[0] + ssq[1] + ssq[2];
            const float mean = s * (1.0f / 768.0f);
            const float var  = sq * (1.0f / 768.0f) - mean * mean;
            const float rstd = rsqrtf(var + 1e-5f);
            const float4 gv = *(const float4*)(ln1_g + (t << 2));
            const float4 bv = *(const float4*)(ln1_b + (t << 2));
            short4b o;
            o[0] = f2bf((v.x - mean) * rstd * gv.x + bv.x);
            o[1] = f2bf((v.y - mean) * rstd * gv.y + bv.y);
            o[2] = f2bf((v.z - mean) * rstd * gv.z + bv.z);
            o[3] = f2bf((v.w - mean) * rstd * gv.w + bv.w);
            *(short4b*)(hn1 + (long)row * 768 + (t << 2)) = o;
        }
        return;
    }

    // ---------------- transpose jobs ----------------
    const float* in; short* out; int R, C, ldo, bx, by;
    long ioff = 0, ooff = 0;
    if (bid < 384)       { in = W_embed; out = WembT; R = 2048; C = 768;  ldo = 2048; bx = bid % 12;  by = bid / 12; }
    else if (bid < 768)  { const int l = bid - 384;  in = W1;   out = W1T;  R = 768;  C = 2048; ldo = 768;  bx = l % 32; by = l / 32; }
    else if (bid < 1152) { const int l = bid - 768;  in = W2;   out = W2T;  R = 2048; C = 768;  ldo = 2048; bx = l % 12; by = l / 12; }
    else if (bid < 2304) { const int l = bid - 1152; in = Wo_c; out = WoTc; R = 6144; C = 768;  ldo = 6144; bx = l % 12; by = l / 12; }
    else {  // x transpose: [2304, 10496)
        const int l = bid - 2304;
        const int z = l >> 7, rem = l & 127;
        in = x; out = xT; R = 2048; C = 196; ldo = 2048;
        bx = rem % 4; by = rem / 4;
        ioff = (long)z * 2048 * 196;
        ooff = (long)z * 196 * 2048;
    }

    const int bxo = bx << 6, byo = by << 6;
    const int tx = t & 63, ty = t >> 6;
    #pragma unroll
    for (int i = ty; i < 64; i += 4) {
        const int r = byo + i, c = bxo + tx;
        short v = 0;
        if (r < R && c < C) v = f2bf(in[ioff + (long)r * C + c]);
        tile[i][tx] = v;
    }
    __syncthreads();
    #pragma unroll
    for (int i = ty; i < 64; i += 4) {
        const int c = bxo + i, r = byo + tx;
        if (c < C && r < ldo) out[ooff + (long)c * ldo + r] = tile[tx][i];
    }
}

// ---------------------------------------------------------------------------
// Tiled GEMM:  C[m,n] = act(alpha * sum_k A[m,k]*B[k,n] + bias[n])
//                       + resid[(m % rmod)][n]
//  AM 0: A bf16 row-major [M,K]; AM 1: A f32 row-major [M,K]
//  BM 0: B bf16 BT [N,K];  BM 1: B f32 BT [N,K];  BM 2: B f32 [K,N] (ldb=N-
//        stride; requires n0+128<=N, K%64==0 -- true at all call sites).
// 2-phase dbuf K-loop; LDS-bounce bf16 epilogue (N % 128 == 0 for OUT_BF16).
// ---------------------------------------------------------------------------
template<int ACT, bool OUT_BF16, int TBM, int AM = 0, int BMODE = 0>
__global__ __launch_bounds__(256)
void gemm_kernel(const void* __restrict__ Ap, const void* __restrict__ Bp,
                 const float* __restrict__ bias, const float* __restrict__ resid,
                 int rmod, void* __restrict__ Cp,
                 int M, int N, int K, int Mpad, int Npad,
                 int lda, int ldb, int ldc, int inner_batch,
                 long sA1, long sA2, long sB1, long sB2, long sC1, long sC2,
                 float alpha)
{
    constexpr int BK_ = 64;
    constexpr int MI  = TBM / 32;
    constexpr int BLD = (BMODE == 2) ? 66 : 64;   // pad-66: b128 reads conflict-free
    constexpr int ATS = TBM * BK_;
    constexpr int BTS = 128 * BLD;
    __shared__ __align__(16) short lds_all[2 * (ATS + BTS)];

    const int gx = gridDim.x, gy = gridDim.y;
    const long nwg = (long)gx * gy * gridDim.z;
    const long dfl = blockIdx.x + (long)gx * (blockIdx.y + (long)gy * blockIdx.z);
    const long qch = nwg >> 3, rch = nwg & 7;
    const long xcd = dfl & 7, idx = dfl >> 3;
    const long w = (xcd < rch ? xcd * (qch + 1) : rch * (qch + 1) + (xcd - rch) * qch) + idx;
    const int bx = (int)(w % gx);
    const long wt = w / gx;
    const int by = (int)(wt % gy);
    const int bz = (int)(wt / gy);

    const int outer = bz / inner_batch;
    const int inner = bz - outer * inner_batch;
    const long aoff = (long)outer * sA1 + (long)inner * sA2;
    const long boff = (long)outer * sB1 + (long)inner * sB2;
    const long coff = (long)outer * sC1 + (long)inner * sC2;
    const int m0 = by * TBM, n0 = bx * 128;
    const int tid = threadIdx.x;
    const int wid = tid >> 6, lane = tid & 63;
    const int wm = (wid >> 1) * (TBM / 2);
    const int wn = (wid & 1) << 6;
    const int fr = lane & 15;
    const int fk = (lane >> 4) << 3;

    const int rowp = tid >> 3;
    const int col8 = (tid & 7) << 3;
    const int wrow = (tid >> 6) << 3;

    const bool fastA0 = (m0 + TBM <= Mpad);
    const bool fastB0 = (n0 + 128 <= Npad);

    auto stage = [&](int buf, int kt) {
        short* As = lds_all + buf * (ATS + BTS);
        short* Bs = As + ATS;
        // ---------------- stage A ----------------
        if constexpr (AM == 0) {
            const short* A = (const short*)Ap + aoff;
            if (fastA0 && (kt + BK_ <= K)) {
                const short* src = A + (long)(m0 + rowp) * lda + kt + col8;
                const long rstride = (long)lda << 5;
                #pragma unroll
                for (int p = 0; p < TBM / 32; ++p)
                    gld_lds16(src + p * rstride, As + ((p << 5) + wrow) * BK_);
            } else {
                #pragma unroll
                for (int i = 0; i < TBM / 32; ++i) {
                    const int row = rowp + (i << 5);
                    const int gm = m0 + row, gk = kt + col8;
                    short8 v;
                    if (gm < M && gk + 8 <= K) {
                        v = *(const short8*)(A + (long)gm * lda + gk);
                    } else {
                        #pragma unroll
                        for (int j = 0; j < 8; ++j)
                            v[j] = (gm < M && gk + j < K) ? A[(long)gm * lda + gk + j] : (short)0;
                    }
                    *(short8*)(As + row * BK_ + col8) = v;
                }
            }
        } else {  // AM == 1: f32 row-major (K % 64 == 0 assumed)
            const float* A = (const float*)Ap + aoff;
            const int r0 = tid >> 4, c4 = (tid & 15) << 2;
            #pragma unroll
            for (int i = 0; i < TBM / 16; ++i) {
                const int row = r0 + (i << 4);
                const int gm = m0 + row, gk = kt + c4;
                float4 v = {0.f, 0.f, 0.f, 0.f};
                if (gm < M) v = *(const float4*)(A + (long)gm * lda + gk);
                short4b s; s[0] = f2bf(v.x); s[1] = f2bf(v.y); s[2] = f2bf(v.z); s[3] = f2bf(v.w);
                *(short4b*)(As + row * BK_ + c4) = s;
            }
        }
        // ---------------- stage B ----------------
        if constexpr (BMODE == 0) {
            const short* B = (const short*)Bp + boff;
            if (fastB0 && (kt + BK_ <= K)) {
                const short* src = B + (long)(n0 + rowp) * ldb + kt + col8;
                const long rstride = (long)ldb << 5;
                #pragma unroll
                for (int p = 0; p < 4; ++p)
                    gld_lds16(src + p * rstride, Bs + ((p << 5) + wrow) * BLD);
            } else {
                #pragma unroll
                for (int i = 0; i < 4; ++i) {
                    const int row = rowp + (i << 5);
                    const int gn = n0 + row, gk = kt + col8;
                    short8 v;
                    if (gn < N && gk + 8 <= K) {
                        v = *(const short8*)(B + (long)gn * ldb + gk);
                    } else {
                        #pragma unroll
                        for (int j = 0; j < 8; ++j)
                            v[j] = (gn < N && gk + j < K) ? B[(long)gn * ldb + gk + j] : (short)0;
                    }
                    *(short8*)(Bs + row * BLD + col8) = v;
                }
            }
        } else if constexpr (BMODE == 1) {  // f32 BT [N,K]
            const float* B = (const float*)Bp + boff;
            const int r0 = tid >> 4, c4 = (tid & 15) << 2;
            #pragma unroll
            for (int i = 0; i < 8; ++i) {
                const int row = r0 + (i << 4);
                const int gn = n0 + row, gk = kt + c4;
                float4 v = {0.f, 0.f, 0.f, 0.f};
                if (gn < N) v = *(const float4*)(B + (long)gn * ldb + gk);
                short4b s; s[0] = f2bf(v.x); s[1] = f2bf(v.y); s[2] = f2bf(v.z); s[3] = f2bf(v.w);
                *(short4b*)(Bs + row * BLD + c4) = s;
            }
        } else {  // BMODE == 2: f32 [K,N], ldb = N-stride; n0+128<=N, K%64==0
            const float* B = (const float*)Bp + boff;
            const int kr = tid >> 5, nc = (tid & 31) << 2;
            #pragma unroll
            for (int i = 0; i < 8; ++i) {
                const int k = kr + (i << 3);
                const float4 v = *(const float4*)(B + (long)(kt + k) * ldb + n0 + nc);
                Bs[(nc + 0) * BLD + k] = f2bf(v.x);
                Bs[(nc + 1) * BLD + k] = f2bf(v.y);
                Bs[(nc + 2) * BLD + k] = f2bf(v.z);
                Bs[(nc + 3) * BLD + k] = f2bf(v.w);
            }
        }
    };

    floatx4 acc[MI][4] = {};
    const int nk = K / BK_;

    stage(0, 0);
    __syncthreads();
    for (int t = 0; t < nk; ++t) {
        const int cur = t & 1;
        if (t + 1 < nk) stage(cur ^ 1, (t + 1) * BK_);
        const short* As = lds_all + cur * (ATS + BTS);
        const short* Bs = As + ATS;
        #pragma unroll
        for (int kk = 0; kk < BK_; kk += 32) {
            short8 af[MI], bfv[4];
            #pragma unroll
            for (int i = 0; i < MI; ++i)
                af[i] = *(const short8*)(As + (wm + (i << 4) + fr) * BK_ + kk + fk);
            #pragma unroll
            for (int j = 0; j < 4; ++j)
                bfv[j] = *(const short8*)(Bs + (wn + (j << 4) + fr) * BLD + kk + fk);
            #pragma unroll
            for (int i = 0; i < MI; ++i)
                #pragma unroll
                for (int j = 0; j < 4; ++j)
                    acc[i][j] = __builtin_amdgcn_mfma_f32_16x16x32_bf16(af[i], bfv[j], acc[i][j], 0, 0, 0);
        }
        __syncthreads();
    }

    if constexpr (OUT_BF16) {
        short (*Cl)[128] = reinterpret_cast<short (*)[128]>(lds_all);
        #pragma unroll
        for (int j = 0; j < 4; ++j) {
            const int lcol = wn + (j << 4) + fr;
            const float bv = bias ? bias[n0 + lcol] : 0.0f;
            #pragma unroll
            for (int i = 0; i < MI; ++i) {
                #pragma unroll
                for (int r = 0; r < 4; ++r) {
                    const int lrow = wm + (i << 4) + ((lane >> 4) << 2) + r;
                    float v = acc[i][j][r] * alpha + bv;
                    if constexpr (ACT == 1) v = fmaxf(v, 0.0f);
                    if constexpr (ACT == 2) {
                        v = 0.5f * v * (1.0f + tanhf(0.7978845608028654f * (v + 0.044715f * v * v * v)));
                    }
                    if (resid)
                        v += resid[(long)((m0 + lrow) % rmod) * ldc + n0 + lcol];
                    Cl[lrow][lcol] = f2bf(v);
                }
            }
        }
        __syncthreads();
        const int pr = tid >> 4;
        const int pc = (tid & 15) << 3;
        #pragma unroll
        for (int it = 0; it < TBM / 16; ++it) {
            const int row = (it << 4) + pr;
            const int gm = m0 + row;
            if (gm < M)
                *(short8*)((short*)Cp + coff + (long)gm * ldc + n0 + pc) =
                    *(const short8*)(&Cl[row][pc]);
        }
    } else {
        #pragma unroll
        for (int j = 0; j < 4; ++j) {
            const int col = n0 + wn + (j << 4) + fr;
            if (col >= N) continue;
            const float bv = bias ? bias[col] : 0.0f;
            #pragma unroll
            for (int i = 0; i < MI; ++i) {
                #pragma unroll
                for (int r = 0; r < 4; ++r) {
                    const int row = m0 + wm + (i << 4) + ((lane >> 4) << 2) + r;
                    if (row >= M) continue;
                    float v = acc[i][j][r] * alpha + bv;
                    if constexpr (ACT == 1) v = fmaxf(v, 0.0f);
                    if constexpr (ACT == 2) {
                        v = 0.5f * v * (1.0f + tanhf(0.7978845608028654f * (v + 0.044715f * v * v * v)));
                    }
                    const long ci = coff + (long)row * ldc + col;
                    if (resid) v += resid[(long)(row % rmod) * ldc + col];
                    ((float*)Cp)[ci] = v;
                }
            }
        }
    }
}

// ---------------------------------------------------------------------------
// 256-thread fused attention (self-attn): block = (b,h) x column-slice.
// ---------------------------------------------------------------------------
template<int NTT, int RI>
__global__ __launch_bounds__(256)
void attn_kernel(const short* __restrict__ Qp, const short* __restrict__ Kp,
                 const short* __restrict__ VTp, short* __restrict__ Cp,
                 int nt, int nh,
                 int ldq, int ldk, int ldv, int ldc,
                 int khs, int vhs,
                 long sK, long sVT, long sC,
                 float scale)
{
    constexpr int KP   = NTT * 16;
    constexpr int PLD  = KP + 8;
    constexpr int ROWS = RI * 64;
    constexpr int KS_SH = KP * 64;
    constexpr int P_SH  = ROWS * PLD;
    constexpr int LDS_SH = (KS_SH > P_SH) ? KS_SH : P_SH;
    __shared__ __align__(16) short lds[LDS_SH];
    short (*Pl)[PLD] = reinterpret_cast<short (*)[PLD]>(lds);

    const int blk = blockIdx.x;
    const int nb = gridDim.x / nh;
    int b, h;
    if (nb == 64) {
        b = ((blk & 7) << 3) + (blk >> 6);
        h = (blk >> 3) & 7;
    } else {
        b = blk / nh; h = blk - b * nh;
    }
    const int row0 = blockIdx.z * ROWS;

    const int tid = threadIdx.x, wid = tid >> 6, lane = tid & 63;
    const int fr = lane & 15;
    const int g4 = (lane >> 4) << 2;
    const int fk = (lane >> 4) << 3;

    const short* Qh = Qp + h * 768;
    const short* Kb = Kp + (long)b * sK + h * khs;
    const short* Vb = VTp + (long)b * sVT + (long)h * vhs * ldv;

    const int wmA = wid * (RI * 16);
    floatx4 accS[RI][NTT];
    #pragma unroll
    for (int i = 0; i < RI; ++i)
        #pragma unroll
        for (int j = 0; j < NTT; ++j) accS[i][j] = (floatx4){0.f, 0.f, 0.f, 0.f};

    const short* qrow[RI];
    #pragma unroll
    for (int i = 0; i < RI; ++i)
        qrow[i] = Qh + (long)(row0 + wmA + i * 16 + fr) * ldq + fk;

    const int rowg  = (wid << 3) + (lane >> 3);
    const int slotx = ((lane & 7) ^ ((lane >> 3) & 7)) << 3;
    const short* ksrc = Kb + (long)rowg * ldk + slotx;
    short* kdst0 = lds + (wid << 9);

    for (int t = 0; t < 12; ++t) {
        const int kt = t << 6;
        #pragma unroll
        for (int p = 0; p < KP / 32; ++p)
            gld_lds16(ksrc + ((long)(p << 5) * ldk + kt), kdst0 + (p << 11));
        __syncthreads();
        #pragma unroll
        for (int kkb = 0; kkb < 2; ++kkb) {
            const int kk = kkb << 5;
            short8 aF[RI];
            #pragma unroll
            for (int i = 0; i < RI; ++i)
                aF[i] = *(const short8*)(qrow[i] + kt + kk);
            const int sl = ((((kk >> 3) + (lane >> 4)) ^ (fr & 7)) << 3);
            #pragma unroll
            for (int j = 0; j < NTT; ++j) {
                const short8 bF = *(const short8*)(lds + ((j << 4) + fr) * 64 + sl);
                #pragma unroll
                for (int i = 0; i < RI; ++i)
                    accS[i][j] = __builtin_amdgcn_mfma_f32_16x16x32_bf16(aF[i], bF, accS[i][j], 0, 0, 0);
            }
        }
        __syncthreads();
    }

    float inv[RI][4];
    #pragma unroll
    for (int i = 0; i < RI; ++i) {
        #pragma unroll
        for (int r = 0; r < 4; ++r) {
            float m = -1e30f;
            #pragma unroll
            for (int j = 0; j < NTT; ++j) {
                const int col = j * 16 + fr;
                if (col < nt) m = fmaxf(m, accS[i][j][r]);
            }
            #pragma unroll
            for (int off = 1; off < 16; off <<= 1) m = fmaxf(m, __shfl_xor(m, off));
            float s = 0.0f;
            #pragma unroll
            for (int j = 0; j < NTT; ++j) {
                const int col = j * 16 + fr;
                float e = (col < nt) ? __expf((accS[i][j][r] - m) * scale) : 0.0f;
                accS[i][j][r] = e;
                s += e;
            }
            #pragma unroll
            for (int off = 1; off < 16; off <<= 1) s += __shfl_xor(s, off);
            inv[i][r] = 1.0f / s;
        }
    }

    #pragma unroll
    for (int i = 0; i < RI; ++i)
        #pragma unroll
        for (int j = 0; j < NTT; ++j)
            #pragma unroll
            for (int r = 0; r < 4; ++r)
                Pl[wmA + i * 16 + g4 + r][j * 16 + fr] = f2bf(accS[i][j][r] * inv[i][r]);
    __syncthreads();

    constexpr int WGN = (RI == 2) ? 2 : 4;
    constexpr int NSTEP = WGN * 64;
    const int wm2 = (wid / WGN) << 6;
    const int wn2 = (wid % WGN) << 6;
    short* Cb = Cp + (long)b * sC + h * 768;

    const int chunk = 768 / gridDim.y;
    const int n0b = blockIdx.y * chunk;
    for (int n0 = n0b; n0 < n0b + chunk; n0 += NSTEP) {
        floatx4 acc2[4][4];
        #pragma unroll
        for (int i = 0; i < 4; ++i)
            #pragma unroll
            for (int j = 0; j < 4; ++j) acc2[i][j] = (floatx4){0.f, 0.f, 0.f, 0.f};
        #pragma unroll
        for (int kk = 0; kk < KP; kk += 32) {
            short8 aF[4], bF[4];
            #pragma unroll
            for (int i = 0; i < 4; ++i)
                aF[i] = *(const short8*)(&Pl[wm2 + i * 16 + fr][kk + fk]);
            #pragma unroll
            for (int j = 0; j < 4; ++j)
                bF[j] = *(const short8*)(Vb + (long)(n0 + wn2 + j * 16 + fr) * ldv + kk + fk);
            #pragma unroll
            for (int i = 0; i < 4; ++i)
                #pragma unroll
                for (int j = 0; j < 4; ++j)
                    acc2[i][j] = __builtin_amdgcn_mfma_f32_16x16x32_bf16(aF[i], bF[j], acc2[i][j], 0, 0, 0);
        }
        #pragma unroll
        for (int j = 0; j < 4; ++j) {
            const int col = n0 + wn2 + (j << 4) + fr;
            #pragma unroll
            for (int i = 0; i < 4; ++i) {
                #pragma unroll
                for (int r = 0; r < 4; ++r) {
                    const int row = row0 + wm2 + (i << 4) + g4 + r;
                    if (row < 100)
                        Cb[(long)row * ldc + col] = f2bf(acc2[i][j][r]);
                }
            }
        }
    }
}

// ---------------------------------------------------------------------------
// 512-thread fused cross-attention: block = (b, h), 128 Q-rows, 8 waves.
// ---------------------------------------------------------------------------
template<int NTT>
__global__ __launch_bounds__(512)
void attn8_kernel(const short* __restrict__ Qp, const short* __restrict__ Kp,
                  const short* __restrict__ VTp, short* __restrict__ Cp,
                  int nt, int ldq, int ldk, int ldv, int ldc,
                  long sK, long sVT, long sC, float scale)
{
    constexpr int KP   = NTT * 16;        // 224
    constexpr int PLD  = KP + 8;          // 232
    constexpr int KBUF = KP * 64;
    constexpr int P_SH = 128 * PLD;
    constexpr int LDS_SH = (2 * KBUF > P_SH) ? 2 * KBUF : P_SH;
    __shared__ __align__(16) short lds[LDS_SH];
    short (*Pl)[PLD] = reinterpret_cast<short (*)[PLD]>(lds);

    const int blk = blockIdx.x;
    const int b = ((blk & 7) << 3) + (blk >> 6);
    const int h = (blk >> 3) & 7;

    const int tid = threadIdx.x, wid = tid >> 6, lane = tid & 63;
    const int fr = lane & 15;
    const int g4 = (lane >> 4) << 2;
    const int fk = (lane >> 4) << 3;

    const short* Qh = Qp + h * 768;
    const short* Kb = Kp + (long)b * sK;
    const short* Vb = VTp + (long)b * sVT;

    const int wmA = wid << 4;
    floatx4 accS[NTT];
    #pragma unroll
    for (int j = 0; j < NTT; ++j) accS[j] = (floatx4){0.f, 0.f, 0.f, 0.f};

    const short* qrow = Qh + (long)(wmA + fr) * ldq + fk;

    const int rowg  = (wid << 3) + (lane >> 3);
    const int slotx = ((lane & 7) ^ ((lane >> 3) & 7)) << 3;
    const short* ksrc = Kb + (long)rowg * ldk + slotx;

    auto stageK = [&](int buf, int kt) {
        short* dst = lds + buf * KBUF + (wid << 9);
        #pragma unroll
        for (int p = 0; p < 4; ++p)
            if (p < 3 || wid < 4)
                gld_lds16(ksrc + ((long)(p << 6) * ldk + kt), dst + (p << 12));
    };

    stageK(0, 0);
    __syncthreads();
    for (int t = 0; t < 12; ++t) {
        const int cur = t & 1;
        if (t < 11) stageK(cur ^ 1, (t + 1) << 6);
        const int kt = t << 6;
        const short* kb = lds + cur * KBUF;
        #pragma unroll
        for (int kkb = 0; kkb < 2; ++kkb) {
            const int kk = kkb << 5;
            const short8 aF = *(const short8*)(qrow + kt + kk);
            const int sl = ((((kk >> 3) + (lane >> 4)) ^ (fr & 7)) << 3);
            #pragma unroll
            for (int j = 0; j < NTT; ++j) {
                const short8 bF = *(const short8*)(kb + ((j << 4) + fr) * 64 + sl);
                accS[j] = __builtin_amdgcn_mfma_f32_16x16x32_bf16(aF, bF, accS[j], 0, 0, 0);
            }
        }
        __syncthreads();
    }

    float inv_[4];
    #pragma unroll
    for (int r = 0; r < 4; ++r) {
        float m = -1e30f;
        #pragma unroll
        for (int j = 0; j < NTT; ++j) {
            const int col = j * 16 + fr;
            if (col < nt) m = fmaxf(m, accS[j][r]);
        }
        #pragma unroll
        for (int off = 1; off < 16; off <<= 1) m = fmaxf(m, __shfl_xor(m, off));
        float s = 0.0f;
        #pragma unroll
        for (int j = 0; j < NTT; ++j) {
            const int col = j * 16 + fr;
            float e = (col < nt) ? __expf((accS[j][r] - m) * scale) : 0.0f;
            accS[j][r] = e;
            s += e;
        }
        #pragma unroll
        for (int off = 1; off < 16; off <<= 1) s += __shfl_xor(s, off);
        inv_[r] = 1.0f / s;
    }

    #pragma unroll
    for (int j = 0; j < NTT; ++j)
        #pragma unroll
        for (int r = 0; r < 4; ++r)
            Pl[wmA + g4 + r][j * 16 + fr] = f2bf(accS[j][r] * inv_[r]);
    __syncthreads();

    const int wm2 = (wid >> 2) << 6;
    const int wn2 = (wid & 3) << 6;
    short* Cb = Cp + (long)b * sC + h * 768;

    for (int n0 = 0; n0 < 768; n0 += 256) {
        #pragma unroll
        for (int jh = 0; jh < 2; ++jh) {
            floatx4 acc2[4][2];
            #pragma unroll
            for (int i = 0; i < 4; ++i)
                #pragma unroll
                for (int j = 0; j < 2; ++j) acc2[i][j] = (floatx4){0.f, 0.f, 0.f, 0.f};
            #pragma unroll
            for (int kk = 0; kk < KP; kk += 32) {
                short8 aF[4], bF[2];
                #pragma unroll
                for (int i = 0; i < 4; ++i)
                    aF[i] = *(const short8*)(&Pl[wm2 + i * 16 + fr][kk + fk]);
                #pragma unroll
                for (int j = 0; j < 2; ++j)
                    bF[j] = *(const short8*)(Vb + (long)(n0 + wn2 + (jh * 2 + j) * 16 + fr) * ldv + kk + fk);
                #pragma unroll
                for (int i = 0; i < 4; ++i)
                    #pragma unroll
                    for (int j = 0; j < 2; ++j)
                        acc2[i][j] = __builtin_amdgcn_mfma_f32_16x16x32_bf16(aF[i], bF[j], acc2[i][j], 0, 0, 0);
            }
            #pragma unroll
            for (int j = 0; j < 2; ++j) {
                const int col = n0 + wn2 + ((jh * 2 + j) << 4) + fr;
                #pragma unroll
                for (int i = 0; i < 4; ++i) {
                    #pragma unroll
                    for (int r = 0; r < 4; ++r) {
                        const int row = wm2 + (i << 4) + g4 + r;
                        if (row < 100)
                            Cb[(long)row * ldc + col] = f2bf(acc2[i][j][r]);
                    }
                }
            }
        }
    }
}

// ---------------------------------------------------------------------------
// Batched transpose: in [R,Cc] (f32 or bf16) -> out [Cc][ldout] bf16.
// ---------------------------------------------------------------------------
template<bool IN_F32>
__global__ __launch_bounds__(256)
void transpose_kernel(const void* __restrict__ inp, short* __restrict__ outp,
                      int R, int Cc, int ldout)
{
    __shared__ short tile[64][65];
    const long in_off = (long)blockIdx.z * R * Cc;
    const long out_off = (long)blockIdx.z * Cc * ldout;
    const int bx = blockIdx.x << 6;
    const int by = blockIdx.y << 6;
    const int tx = threadIdx.x & 63, ty = threadIdx.x >> 6;
    #pragma unroll
    for (int i = ty; i < 64; i += 4) {
        const int r = by + i, c = bx + tx;
        short v = 0;
        if (r < R && c < Cc) {
            if constexpr (IN_F32) v = f2bf(((const float*)inp)[in_off + (long)r * Cc + c]);
            else                  v = ((const short*)inp)[in_off + (long)r * Cc + c];
        }
        tile[i][tx] = v;
    }
    __syncthreads();
    #pragma unroll
    for (int i = ty; i < 64; i += 4) {
        const int c = bx + i, r = by + tx;
        if (c < Cc && r < ldout) outp[out_off + (long)c * ldout + r] = tile[tx][i];
    }
}

// ---------------------------------------------------------------------------
// Split-K reduce + bias + residual (+ optional LayerNorm).
// ---------------------------------------------------------------------------
template<bool DO_LN, bool PBF16>
__global__ __launch_bounds__(192)
void reduce_kernel(const void* __restrict__ part, int nsplit, long pstride,
                   const float* __restrict__ resid, int rmod,
                   const float* __restrict__ bias,
                   const float* __restrict__ g, const float* __restrict__ bvec,
                   float* __restrict__ hout, short* __restrict__ hnout)
{
    const long row = blockIdx.x;
    const int t = threadIdx.x;
    const int c = t << 2;
    const float* rr = resid + (long)(row % rmod) * 768;
    float4 v = *(const float4*)(rr + c);
    const float4 bb = *(const float4*)(bias + c);
    v.x += bb.x; v.y += bb.y; v.z += bb.z; v.w += bb.w;
    for (int s = 0; s < nsplit; ++s) {
        const long idx = (long)s * pstride + row * 768 + c;
        if constexpr (PBF16) {
            const short4b p = *(const short4b*)((const short*)part + idx);
            v.x += bf2f(p[0]); v.y += bf2f(p[1]); v.z += bf2f(p[2]); v.w += bf2f(p[3]);
        } else {
            const float4 p = *(const float4*)((const float*)part + idx);
            v.x += p.x; v.y += p.y; v.z += p.z; v.w += p.w;
        }
    }
    *(float4*)(hout + row * 768 + c) = v;
    if constexpr (DO_LN) {
        float s  = v.x + v.y + v.z + v.w;
        float sq = v.x * v.x + v.y * v.y + v.z * v.z + v.w * v.w;
        #pragma unroll
        for (int off = 32; off; off >>= 1) {
            s  += __shfl_xor(s, off);
            sq += __shfl_xor(sq, off);
        }
        __shared__ float ss[4], ssq[4];
        const int wv = t >> 6;
        if ((t & 63) == 0) { ss[wv] = s; ssq[wv] = sq; }
        __syncthreads();
        s  = ss[0] + ss[1] + ss[2];
        sq = ssq[0] + ssq[1] + ssq[2];
        const float mean = s * (1.0f / 768.0f);
        const float var  = sq * (1.0f / 768.0f) - mean * mean;
        const float rstd = rsqrtf(var + 1e-5f);
        const float4 gv = *(const float4*)(g + c);
        const float4 bv = *(const float4*)(bvec + c);
        short4b o;
        o[0] = f2bf((v.x - mean) * rstd * gv.x + bv.x);
        o[1] = f2bf((v.y - mean) * rstd * gv.y + bv.y);
        o[2] = f2bf((v.z - mean) * rstd * gv.z + bv.z);
        o[3] = f2bf((v.w - mean) * rstd * gv.w + bv.w);
        *(short4b*)(hnout + row * 768 + c) = o;
    }
}

// ---------------------------------------------------------------------------
__global__ __launch_bounds__(192)
void reducen_kernel(const short* __restrict__ part, int nsplit, long pstride,
                    short* __restrict__ out, int grps)
{
    const int blk = blockIdx.x;
    const int row = blk / grps, grp = blk - row * grps;
    const long base = (long)row * grps * 768 + grp * 768 + (threadIdx.x << 2);
    float4 v = {0.f, 0.f, 0.f, 0.f};
    for (int s = 0; s < nsplit; ++s) {
        const short4b p = *(const short4b*)(part + (long)s * pstride + base);
        v.x += bf2f(p[0]); v.y += bf2f(p[1]); v.z += bf2f(p[2]); v.w += bf2f(p[3]);
    }
    short4b o;
    o[0] = f2bf(v.x); o[1] = f2bf(v.y); o[2] = f2bf(v.z); o[3] = f2bf(v.w);
    *(short4b*)(out + base) = o;
}

// ---------------------------------------------------------------------------
__global__ __launch_bounds__(64)
void groupfc_kernel(const float* __restrict__ h, const float* __restrict__ dp,
                    const float* __restrict__ bias, float* __restrict__ out)
{
    const int bg = blockIdx.x;
    const int g = bg % 100;
    const int t = threadIdx.x;
    const float* hr = h + (long)bg * 768;
    const float* d = dp + (long)g * 7680;
    float acc[10];
    #pragma unroll
    for (int f = 0; f < 10; ++f) acc[f] = 0.0f;
    for (int k = t; k < 768; k += 64) {
        const float hv = hr[k];
        const float* dr = d + k * 10;
        #pragma unroll
        for (int f = 0; f < 10; ++f) acc[f] += hv * dr[f];
    }
    #pragma unroll
    for (int f = 0; f < 10; ++f) {
        #pragma unroll
        for (int off = 32; off; off >>= 1) acc[f] += __shfl_xor(acc[f], off);
    }
    if (t == 0) {
        const int b = bg / 100;
        #pragma unroll
        for (int f = 0; f < 10; ++f)
            out[(long)b * 1000 + g * 10 + f] = acc[f] + bias[g * 10 + f];
    }
}

// ---------------------------------------------------------------------------
extern "C" void kernel_launch(void* const* d_in, const int* in_sizes, int n_in,
                              void* d_out, int out_size, void* d_ws, size_t ws_size,
                              hipStream_t stream)
{
    const float* x       = (const float*)d_in[0];
    const float* W_embed = (const float*)d_in[1];
    const float* b_embed = (const float*)d_in[2];
    const float* qe      = (const float*)d_in[3];
    const float* ln1_g   = (const float*)d_in[4];
    const float* ln1_b   = (const float*)d_in[5];
    const float* Wq_s    = (const float*)d_in[6];
    const float* Wk_s    = (const float*)d_in[7];
    const float* Wv_s    = (const float*)d_in[8];
    const float* Wo_s    = (const float*)d_in[9];
    const float* bo_s    = (const float*)d_in[10];
    const float* ln2_g   = (const float*)d_in[11];
    const float* ln2_b   = (const float*)d_in[12];
    const float* Wq_c    = (const float*)d_in[13];
    const float* Wk_c    = (const float*)d_in[14];
    const float* Wv_c    = (const float*)d_in[15];
    const float* Wo_c    = (const float*)d_in[16];
    const float* bo_c    = (const float*)d_in[17];
    const float* ln3_g   = (const float*)d_in[18];
    const float* ln3_b   = (const float*)d_in[19];
    const float* W1      = (const float*)d_in[20];
    const float* b1      = (const float*)d_in[21];
    const float* W2      = (const float*)d_in[22];
    const float* b2      = (const float*)d_in[23];
    const float* dpool   = (const float*)d_in[24];
    const float* dbias   = (const float*)d_in[25];

    char* base = (char*)d_ws;
    size_t off = 0;
    auto alloc = [&](size_t bytes) -> void* {
        void* p = base + off;
        off += (bytes + 255) & ~(size_t)255;
        return p;
    };
    short* ek    = (short*)alloc(12544L * 768 * 2);      // emb bf16 [12544][768]
    short* ekT   = (short*)alloc(64L * 768 * 256 * 2);   // emb^T [b][768][256] zero-pad
    short* big   = (short*)alloc(6400L * 6144 * 2);      // xT, then ctx_c
    char*  shr   = (char*) alloc(4L * 6400 * 768 * 4);   // bf16 split-K planes
    float* h2    = (float*)alloc(6400L * 768 * 4);       // residual stream (b-dep)
    short* hn3   = (short*)alloc(6400L * 768 * 2);
    short* t1    = (short*)alloc(6400L * 2048 * 2);
    short* WembT = (short*)alloc(768L * 2048 * 2);
    short* W1T   = (short*)alloc(2048L * 768 * 2);
    short* W2T   = (short*)alloc(768L * 2048 * 2);
    short* WqkTc = (short*)alloc(6144L * 768 * 2);       // [h][768][768] planes
    short* WvoTc = (short*)alloc(768L * 6144 * 2);
    short* WoTc  = (short*)alloc(768L * 6144 * 2);       // Wo_c^T bf16
    short* hn1   = (short*)alloc(128L * 768 * 2);        // pad rows stale (finite)
    short* q_s   = (short*)alloc(128L * 6144 * 2);       // consecutive: q_s/k_s/v_s
    short* k_s   = (short*)alloc(128L * 6144 * 2);
    short* v_s   = (short*)alloc(128L * 6144 * 2);
    short* ctx_s = (short*)alloc(128L * 6144 * 2);
    short* v_sT  = (short*)alloc(6144L * 128 * 2);       // zero-pad cols >= 100
    short* qt_c  = (short*)alloc(128L * 6144 * 2);
    short* qtP   = (short*)alloc(4L * 100 * 6144 * 2);   // qt split-K partials bf16
    float* partS = (float*)alloc(8L * 100 * 768 * 4);
    float* h1    = (float*)alloc(128L * 768 * 4);
    short* hn2   = (short*)alloc(128L * 768 * 2);
    (void)ws_size; (void)in_sizes; (void)n_in; (void)out_size;

    short* partCb = (short*)shr;                         // [8][6400][768] bf16

    const float scale = 0.03608439182435161f;  // 768^-0.5

    // ================= merged prep (5 transposes + x + LN1) =================
    short* xT = big;  // [12544][2048] bf16
    prep_kernel<<<dim3(10596), 256, 0, stream>>>(
        W_embed, W1, W2, Wo_c, x, qe, ln1_g, ln1_b,
        WembT, W1T, W2T, WoTc, xT, hn1);

    // ---- combined cross weights (A/B read f32 inputs directly) ----
    // WqkTc[h][e][d] = sum_f Wk_c[e, hf] * Wq_c[d, hf]
    gemm_kernel<0, true, 128, 1, 1><<<dim3(6, 6, 8), 256, 0, stream>>>(
        Wk_c, Wq_c, nullptr, nullptr, 1, WqkTc,
        768, 768, 768, 768, 768, 6144, 6144, 768, 8,
        0L, 768L, 0L, 768L, 0L, 589824L, 1.0f);
    // WvoTc[d'][h*768+e] = sum_f WoTc[d', hf] * Wv_c[e, hf]
    gemm_kernel<0, true, 128, 0, 1><<<dim3(6, 6, 8), 256, 0, stream>>>(
        WoTc, Wv_c, nullptr, nullptr, 1, WvoTc,
        768, 768, 768, 768, 768, 6144, 6144, 6144, 8,
        0L, 768L, 0L, 768L, 0L, 768L, 1.0f);

    // ================= embed =================
    gemm_kernel<1, true, 64><<<dim3(6, 196, 1), 256, 0, stream>>>(
        xT, WembT, b_embed, nullptr, 1, ek,
        12544, 768, 2048, 12544, 768, 2048, 2048, 768, 1,
        0L, 0L, 0L, 0L, 0L, 0L, 1.0f);
    transpose_kernel<false><<<dim3(12, 4, 64), 256, 0, stream>>>(ek, ekT, 196, 768, 256);

    // ================= self-attention (batch-invariant, 100 rows) ==========
    // q/k/v projections: B = W?_s f32 [K=768][N=6144] read directly (BM2)
    gemm_kernel<0, true, 128, 0, 2><<<dim3(48, 1, 1), 256, 0, stream>>>(
        hn1, Wq_s, nullptr, nullptr, 1, q_s,
        100, 6144, 768, 128, 6144, 768, 6144, 6144, 1, 0,0,0,0,0,0, 1.0f);
    gemm_kernel<0, true, 128, 0, 2><<<dim3(48, 1, 1), 256, 0, stream>>>(
        hn1, Wk_s, nullptr, nullptr, 1, k_s,
        100, 6144, 768, 128, 6144, 768, 6144, 6144, 1, 0,0,0,0,0,0, 1.0f);
    gemm_kernel<0, true, 128, 0, 2><<<dim3(48, 1, 1), 256, 0, stream>>>(
        hn1, Wv_s, nullptr, nullptr, 1, v_s,
        100, 6144, 768, 128, 6144, 768, 6144, 6144, 1, 0,0,0,0,0,0, 1.0f);
    transpose_kernel<false><<<dim3(96, 2, 1), 256, 0, stream>>>(v_s, v_sT, 100, 6144, 128);
    attn_kernel<8, 2><<<dim3(8, 6, 1), 256, 0, stream>>>(
        q_s, k_s, v_sT, ctx_s,
        100, 8, 6144, 6144, 128, 6144,
        768, 768, 0L, 0L, 0L, scale);
    // o_s: B = Wo_s f32 [K=6144][N=768] (BM2), split-K=8 (chunk 768 rows)
    gemm_kernel<0, false, 128, 0, 2><<<dim3(6, 1, 8), 256, 0, stream>>>(
        ctx_s, Wo_s, nullptr, nullptr, 1, partS,
        100, 768, 768, 128, 768, 6144, 768, 768, 8,
        0L, 768L, 0L, 589824L, 0L, 76800L, 1.0f);
    reduce_kernel<true, false><<<dim3(100), 192, 0, stream>>>(
        partS, 8, 76800L, qe, 100, bo_s, ln2_g, ln2_b, h1, hn2);

    // ================= cross-attention =================
    gemm_kernel<0, true, 128><<<dim3(48, 1, 4), 256, 0, stream>>>(
        hn2, WqkTc, nullptr, nullptr, 1, qtP,
        100, 6144, 192, 128, 6144, 768, 768, 6144, 4,
        0L, 192L, 0L, 192L, 0L, 614400L, 1.0f);
    reducen_kernel<<<dim3(800), 192, 0, stream>>>(qtP, 4, 614400L, qt_c, 8);
    attn8_kernel<14><<<dim3(512), 512, 0, stream>>>(
        qt_c, ek, ekT, big,
        196, 6144, 768, 256, 6144,
        150528L, 196608L, 614400L, scale);
    gemm_kernel<0, true, 128><<<dim3(6, 50, 8), 256, 0, stream>>>(
        big, WvoTc, nullptr, nullptr, 1, partCb,
        6400, 768, 768, 6400, 768, 6144, 6144, 768, 8,
        0L, 768L, 0L, 768L, 0L, 4915200L, 1.0f);
    reduce_kernel<true, true><<<dim3(6400), 192, 0, stream>>>(
        partCb, 8, 4915200L, h1, 100, bo_c, ln3_g, ln3_b, h2, hn3);

    // ================= MLP =================
    gemm_kernel<2, true, 64><<<dim3(16, 100, 1), 256, 0, stream>>>(
        hn3, W1T, b1, nullptr, 1, t1,
        6400, 2048, 768, 6400, 2048, 768, 768, 2048, 1, 0,0,0,0,0,0, 1.0f);
    gemm_kernel<0, true, 128><<<dim3(6, 50, 4), 256, 0, stream>>>(
        t1, W2T, nullptr, nullptr, 1, partCb,
        6400, 768, 512, 6400, 768, 2048, 2048, 768, 4,
        0L, 512L, 0L, 512L, 0L, 4915200L, 1.0f);
    reduce_kernel<false, true><<<dim3(6400), 192, 0, stream>>>(
        partCb, 4, 4915200L, h2, 6400, b2, nullptr, nullptr, h2, nullptr);

    // ================= GroupFC =================
    groupfc_kernel<<<dim3(6400), 64, 0, stream>>>(h2, dpool, dbias, (float*)d_out);
}

// Round 18
// 956.541 us; speedup vs baseline: 1.1253x; 1.1253x over previous
//
#include <hip/hip_runtime.h>
#include <hip/hip_bf16.h>

// ---------------------------------------------------------------------------
// MLDecoder forward on MI355X (gfx950).  Round 18:
//  - REVERT round-17's BM2 (f32 [K,N]) weight reads in the qkv / o_s GEMMs:
//    48-block latency-bound GEMMs pulled 18.9 MB f32 at 227 GB/s (125 us
//    each, 3.3x regression).  s-weight transposes restored into prep_kernel
//    (15,204 blocks); qkv/o_s back to bf16 BT weights.
//  - KEEP round-17's valid half: combine GEMMs read Wq_c/Wk_c/Wv_c f32
//    directly (AM1/BM1) -- the 13,824 cast blocks stay dead.
// ---------------------------------------------------------------------------

typedef __attribute__((ext_vector_type(8))) short short8;   // 8 bf16
typedef __attribute__((ext_vector_type(4))) short short4b;  // 4 bf16
typedef __attribute__((ext_vector_type(4))) float floatx4;

#define DEVI static __device__ __forceinline__

DEVI short f2bf(float f) {
    union { __hip_bfloat16 h; short s; } u;
    u.h = __float2bfloat16(f);
    return u.s;
}

DEVI float bf2f(short s) {
    union { float f; unsigned u; } v;
    v.u = ((unsigned)(unsigned short)s) << 16;
    return v.f;
}

DEVI void gld_lds16(const void* g, void* l) {
    __builtin_amdgcn_global_load_lds(
        (const __attribute__((address_space(1))) void*)g,
        (__attribute__((address_space(3))) void*)l, 16, 0, 0);
}

// ---------------------------------------------------------------------------
// prep_kernel: input-only prep in one launch.
//   blocks [0,384)       W_embed [2048x768] -> WembT (ld 2048)
//   blocks [384,768)     W1      [768x2048] -> W1T   (ld 768)
//   blocks [768,1152)    W2      [2048x768] -> W2T   (ld 2048)
//   blocks [1152,2304)   Wo_c    [6144x768] -> WoTc  (ld 6144)
//   blocks [2304,3456)   Wq_s    [768x6144] -> WqsT  (ld 768)
//   blocks [3456,4608)   Wk_s               -> WksT
//   blocks [4608,5760)   Wv_s               -> WvsT
//   blocks [5760,6912)   Wo_s    [6144x768] -> WosT  (ld 6144)
//   blocks [6912,15104)  x [64][2048][196]  -> xT [64][196][2048] bf16
//   blocks [15104,15204) LN1(query_embed)   -> hn1 (100 rows)
// ---------------------------------------------------------------------------
__global__ __launch_bounds__(256)
void prep_kernel(const float* __restrict__ W_embed, const float* __restrict__ W1,
                 const float* __restrict__ W2, const float* __restrict__ Wo_c,
                 const float* __restrict__ Wq_s, const float* __restrict__ Wk_s,
                 const float* __restrict__ Wv_s, const float* __restrict__ Wo_s,
                 const float* __restrict__ x,
                 const float* __restrict__ qe, const float* __restrict__ ln1_g,
                 const float* __restrict__ ln1_b,
                 short* __restrict__ WembT, short* __restrict__ W1T,
                 short* __restrict__ W2T, short* __restrict__ WoTc,
                 short* __restrict__ WqsT, short* __restrict__ WksT,
                 short* __restrict__ WvsT, short* __restrict__ WosT,
                 short* __restrict__ xT, short* __restrict__ hn1)
{
    const int bid = blockIdx.x;
    const int t = threadIdx.x;

    __shared__ __align__(16) short tile[64][65];

    // ---------------- LN1 job ----------------
    if (bid >= 15104) {
        const int row = bid - 15104;
        float* ss  = (float*)&tile[0][0];
        float* ssq = ss + 4;
        float4 v = {0.f, 0.f, 0.f, 0.f};
        float s = 0.f, sq = 0.f;
        if (t < 192) {
            v = *(const float4*)(qe + (long)row * 768 + (t << 2));
            s  = v.x + v.y + v.z + v.w;
            sq = v.x * v.x + v.y * v.y + v.z * v.z + v.w * v.w;
            #pragma unroll
            for (int off = 32; off; off >>= 1) {
                s  += __shfl_xor(s, off);
                sq += __shfl_xor(sq, off);
            }
            if ((t & 63) == 0) { ss[t >> 6] = s; ssq[t >> 6] = sq; }
        }
        __syncthreads();
        if (t < 192) {
            s  = ss[0] + ss[1] + ss[2];
            sq = ssq[0] + ssq[1] + ssq[2];
            const float mean = s * (1.0f / 768.0f);
            const float var  = sq * (1.0f / 768.0f) - mean * mean;
            const float rstd = rsqrtf(var + 1e-5f);
            const float4 gv = *(const float4*)(ln1_g + (t << 2));
            const float4 bv = *(const float4*)(ln1_b + (t << 2));
            short4b o;
            o[0] = f2bf((v.x - mean) * rstd * gv.x + bv.x);
            o[1] = f2bf((v.y - mean) * rstd * gv.y + bv.y);
            o[2] = f2bf((v.z - mean) * rstd * gv.z + bv.z);
            o[3] = f2bf((v.w - mean) * rstd * gv.w + bv.w);
            *(short4b*)(hn1 + (long)row * 768 + (t << 2)) = o;
        }
        return;
    }

    // ---------------- transpose jobs ----------------
    const float* in; short* out; int R, C, ldo, bx, by;
    long ioff = 0, ooff = 0;
    if (bid < 384)       { in = W_embed; out = WembT; R = 2048; C = 768;  ldo = 2048; bx = bid % 12;  by = bid / 12; }
    else if (bid < 768)  { const int l = bid - 384;  in = W1;   out = W1T;  R = 768;  C = 2048; ldo = 768;  bx = l % 32; by = l / 32; }
    else if (bid < 1152) { const int l = bid - 768;  in = W2;   out = W2T;  R = 2048; C = 768;  ldo = 2048; bx = l % 12; by = l / 12; }
    else if (bid < 2304) { const int l = bid - 1152; in = Wo_c; out = WoTc; R = 6144; C = 768;  ldo = 6144; bx = l % 12; by = l / 12; }
    else if (bid < 3456) { const int l = bid - 2304; in = Wq_s; out = WqsT; R = 768;  C = 6144; ldo = 768;  bx = l % 96; by = l / 96; }
    else if (bid < 4608) { const int l = bid - 3456; in = Wk_s; out = WksT; R = 768;  C = 6144; ldo = 768;  bx = l % 96; by = l / 96; }
    else if (bid < 5760) { const int l = bid - 4608; in = Wv_s; out = WvsT; R = 768;  C = 6144; ldo = 768;  bx = l % 96; by = l / 96; }
    else if (bid < 6912) { const int l = bid - 5760; in = Wo_s; out = WosT; R = 6144; C = 768;  ldo = 6144; bx = l % 12; by = l / 12; }
    else {  // x transpose: [6912, 15104)
        const int l = bid - 6912;
        const int z = l >> 7, rem = l & 127;
        in = x; out = xT; R = 2048; C = 196; ldo = 2048;
        bx = rem % 4; by = rem / 4;
        ioff = (long)z * 2048 * 196;
        ooff = (long)z * 196 * 2048;
    }

    const int bxo = bx << 6, byo = by << 6;
    const int tx = t & 63, ty = t >> 6;
    #pragma unroll
    for (int i = ty; i < 64; i += 4) {
        const int r = byo + i, c = bxo + tx;
        short v = 0;
        if (r < R && c < C) v = f2bf(in[ioff + (long)r * C + c]);
        tile[i][tx] = v;
    }
    __syncthreads();
    #pragma unroll
    for (int i = ty; i < 64; i += 4) {
        const int c = bxo + i, r = byo + tx;
        if (c < C && r < ldo) out[ooff + (long)c * ldo + r] = tile[tx][i];
    }
}

// ---------------------------------------------------------------------------
// Tiled GEMM:  C[m,n] = act(alpha * sum_k A[m,k]*B[k,n] + bias[n])
//                       + resid[(m % rmod)][n]
//  AM 0: A bf16 row-major [M,K]; AM 1: A f32 row-major [M,K]
//  BM 0: B bf16 BT [N,K];  BM 1: B f32 BT [N,K]
// 2-phase dbuf K-loop; LDS-bounce bf16 epilogue (N % 128 == 0 for OUT_BF16).
// ---------------------------------------------------------------------------
template<int ACT, bool OUT_BF16, int TBM, int AM = 0, int BMODE = 0>
__global__ __launch_bounds__(256)
void gemm_kernel(const void* __restrict__ Ap, const void* __restrict__ Bp,
                 const float* __restrict__ bias, const float* __restrict__ resid,
                 int rmod, void* __restrict__ Cp,
                 int M, int N, int K, int Mpad, int Npad,
                 int lda, int ldb, int ldc, int inner_batch,
                 long sA1, long sA2, long sB1, long sB2, long sC1, long sC2,
                 float alpha)
{
    constexpr int BK_ = 64;
    constexpr int MI  = TBM / 32;
    constexpr int ATS = TBM * BK_;
    constexpr int BTS = 128 * BK_;
    __shared__ __align__(16) short lds_all[2 * (ATS + BTS)];

    const int gx = gridDim.x, gy = gridDim.y;
    const long nwg = (long)gx * gy * gridDim.z;
    const long dfl = blockIdx.x + (long)gx * (blockIdx.y + (long)gy * blockIdx.z);
    const long qch = nwg >> 3, rch = nwg & 7;
    const long xcd = dfl & 7, idx = dfl >> 3;
    const long w = (xcd < rch ? xcd * (qch + 1) : rch * (qch + 1) + (xcd - rch) * qch) + idx;
    const int bx = (int)(w % gx);
    const long wt = w / gx;
    const int by = (int)(wt % gy);
    const int bz = (int)(wt / gy);

    const int outer = bz / inner_batch;
    const int inner = bz - outer * inner_batch;
    const long aoff = (long)outer * sA1 + (long)inner * sA2;
    const long boff = (long)outer * sB1 + (long)inner * sB2;
    const long coff = (long)outer * sC1 + (long)inner * sC2;
    const int m0 = by * TBM, n0 = bx * 128;
    const int tid = threadIdx.x;
    const int wid = tid >> 6, lane = tid & 63;
    const int wm = (wid >> 1) * (TBM / 2);
    const int wn = (wid & 1) << 6;
    const int fr = lane & 15;
    const int fk = (lane >> 4) << 3;

    const int rowp = tid >> 3;
    const int col8 = (tid & 7) << 3;
    const int wrow = (tid >> 6) << 3;

    const bool fastA0 = (m0 + TBM <= Mpad);
    const bool fastB0 = (n0 + 128 <= Npad);

    auto stage = [&](int buf, int kt) {
        short* As = lds_all + buf * (ATS + BTS);
        short* Bs = As + ATS;
        // ---------------- stage A ----------------
        if constexpr (AM == 0) {
            const short* A = (const short*)Ap + aoff;
            if (fastA0 && (kt + BK_ <= K)) {
                const short* src = A + (long)(m0 + rowp) * lda + kt + col8;
                const long rstride = (long)lda << 5;
                #pragma unroll
                for (int p = 0; p < TBM / 32; ++p)
                    gld_lds16(src + p * rstride, As + ((p << 5) + wrow) * BK_);
            } else {
                #pragma unroll
                for (int i = 0; i < TBM / 32; ++i) {
                    const int row = rowp + (i << 5);
                    const int gm = m0 + row, gk = kt + col8;
                    short8 v;
                    if (gm < M && gk + 8 <= K) {
                        v = *(const short8*)(A + (long)gm * lda + gk);
                    } else {
                        #pragma unroll
                        for (int j = 0; j < 8; ++j)
                            v[j] = (gm < M && gk + j < K) ? A[(long)gm * lda + gk + j] : (short)0;
                    }
                    *(short8*)(As + row * BK_ + col8) = v;
                }
            }
        } else {  // AM == 1: f32 row-major (K % 64 == 0 assumed)
            const float* A = (const float*)Ap + aoff;
            const int r0 = tid >> 4, c4 = (tid & 15) << 2;
            #pragma unroll
            for (int i = 0; i < TBM / 16; ++i) {
                const int row = r0 + (i << 4);
                const int gm = m0 + row, gk = kt + c4;
                float4 v = {0.f, 0.f, 0.f, 0.f};
                if (gm < M) v = *(const float4*)(A + (long)gm * lda + gk);
                short4b s; s[0] = f2bf(v.x); s[1] = f2bf(v.y); s[2] = f2bf(v.z); s[3] = f2bf(v.w);
                *(short4b*)(As + row * BK_ + c4) = s;
            }
        }
        // ---------------- stage B ----------------
        if constexpr (BMODE == 0) {
            const short* B = (const short*)Bp + boff;
            if (fastB0 && (kt + BK_ <= K)) {
                const short* src = B + (long)(n0 + rowp) * ldb + kt + col8;
                const long rstride = (long)ldb << 5;
                #pragma unroll
                for (int p = 0; p < 4; ++p)
                    gld_lds16(src + p * rstride, Bs + ((p << 5) + wrow) * BK_);
            } else {
                #pragma unroll
                for (int i = 0; i < 4; ++i) {
                    const int row = rowp + (i << 5);
                    const int gn = n0 + row, gk = kt + col8;
                    short8 v;
                    if (gn < N && gk + 8 <= K) {
                        v = *(const short8*)(B + (long)gn * ldb + gk);
                    } else {
                        #pragma unroll
                        for (int j = 0; j < 8; ++j)
                            v[j] = (gn < N && gk + j < K) ? B[(long)gn * ldb + gk + j] : (short)0;
                    }
                    *(short8*)(Bs + row * BK_ + col8) = v;
                }
            }
        } else {  // BMODE == 1: f32 BT [N,K]
            const float* B = (const float*)Bp + boff;
            const int r0 = tid >> 4, c4 = (tid & 15) << 2;
            #pragma unroll
            for (int i = 0; i < 8; ++i) {
                const int row = r0 + (i << 4);
                const int gn = n0 + row, gk = kt + c4;
                float4 v = {0.f, 0.f, 0.f, 0.f};
                if (gn < N) v = *(const float4*)(B + (long)gn * ldb + gk);
                short4b s; s[0] = f2bf(v.x); s[1] = f2bf(v.y); s[2] = f2bf(v.z); s[3] = f2bf(v.w);
                *(short4b*)(Bs + row * BK_ + c4) = s;
            }
        }
    };

    floatx4 acc[MI][4] = {};
    const int nk = K / BK_;

    stage(0, 0);
    __syncthreads();
    for (int t = 0; t < nk; ++t) {
        const int cur = t & 1;
        if (t + 1 < nk) stage(cur ^ 1, (t + 1) * BK_);
        const short* As = lds_all + cur * (ATS + BTS);
        const short* Bs = As + ATS;
        #pragma unroll
        for (int kk = 0; kk < BK_; kk += 32) {
            short8 af[MI], bfv[4];
            #pragma unroll
            for (int i = 0; i < MI; ++i)
                af[i] = *(const short8*)(As + (wm + (i << 4) + fr) * BK_ + kk + fk);
            #pragma unroll
            for (int j = 0; j < 4; ++j)
                bfv[j] = *(const short8*)(Bs + (wn + (j << 4) + fr) * BK_ + kk + fk);
            #pragma unroll
            for (int i = 0; i < MI; ++i)
                #pragma unroll
                for (int j = 0; j < 4; ++j)
                    acc[i][j] = __builtin_amdgcn_mfma_f32_16x16x32_bf16(af[i], bfv[j], acc[i][j], 0, 0, 0);
        }
        __syncthreads();
    }

    if constexpr (OUT_BF16) {
        short (*Cl)[128] = reinterpret_cast<short (*)[128]>(lds_all);
        #pragma unroll
        for (int j = 0; j < 4; ++j) {
            const int lcol = wn + (j << 4) + fr;
            const float bv = bias ? bias[n0 + lcol] : 0.0f;
            #pragma unroll
            for (int i = 0; i < MI; ++i) {
                #pragma unroll
                for (int r = 0; r < 4; ++r) {
                    const int lrow = wm + (i << 4) + ((lane >> 4) << 2) + r;
                    float v = acc[i][j][r] * alpha + bv;
                    if constexpr (ACT == 1) v = fmaxf(v, 0.0f);
                    if constexpr (ACT == 2) {
                        v = 0.5f * v * (1.0f + tanhf(0.7978845608028654f * (v + 0.044715f * v * v * v)));
                    }
                    if (resid)
                        v += resid[(long)((m0 + lrow) % rmod) * ldc + n0 + lcol];
                    Cl[lrow][lcol] = f2bf(v);
                }
            }
        }
        __syncthreads();
        const int pr = tid >> 4;
        const int pc = (tid & 15) << 3;
        #pragma unroll
        for (int it = 0; it < TBM / 16; ++it) {
            const int row = (it << 4) + pr;
            const int gm = m0 + row;
            if (gm < M)
                *(short8*)((short*)Cp + coff + (long)gm * ldc + n0 + pc) =
                    *(const short8*)(&Cl[row][pc]);
        }
    } else {
        #pragma unroll
        for (int j = 0; j < 4; ++j) {
            const int col = n0 + wn + (j << 4) + fr;
            if (col >= N) continue;
            const float bv = bias ? bias[col] : 0.0f;
            #pragma unroll
            for (int i = 0; i < MI; ++i) {
                #pragma unroll
                for (int r = 0; r < 4; ++r) {
                    const int row = m0 + wm + (i << 4) + ((lane >> 4) << 2) + r;
                    if (row >= M) continue;
                    float v = acc[i][j][r] * alpha + bv;
                    if constexpr (ACT == 1) v = fmaxf(v, 0.0f);
                    if constexpr (ACT == 2) {
                        v = 0.5f * v * (1.0f + tanhf(0.7978845608028654f * (v + 0.044715f * v * v * v)));
                    }
                    const long ci = coff + (long)row * ldc + col;
                    if (resid) v += resid[(long)(row % rmod) * ldc + col];
                    ((float*)Cp)[ci] = v;
                }
            }
        }
    }
}

// ---------------------------------------------------------------------------
// 256-thread fused attention (self-attn): block = (b,h) x column-slice.
// ---------------------------------------------------------------------------
template<int NTT, int RI>
__global__ __launch_bounds__(256)
void attn_kernel(const short* __restrict__ Qp, const short* __restrict__ Kp,
                 const short* __restrict__ VTp, short* __restrict__ Cp,
                 int nt, int nh,
                 int ldq, int ldk, int ldv, int ldc,
                 int khs, int vhs,
                 long sK, long sVT, long sC,
                 float scale)
{
    constexpr int KP   = NTT * 16;
    constexpr int PLD  = KP + 8;
    constexpr int ROWS = RI * 64;
    constexpr int KS_SH = KP * 64;
    constexpr int P_SH  = ROWS * PLD;
    constexpr int LDS_SH = (KS_SH > P_SH) ? KS_SH : P_SH;
    __shared__ __align__(16) short lds[LDS_SH];
    short (*Pl)[PLD] = reinterpret_cast<short (*)[PLD]>(lds);

    const int blk = blockIdx.x;
    const int nb = gridDim.x / nh;
    int b, h;
    if (nb == 64) {
        b = ((blk & 7) << 3) + (blk >> 6);
        h = (blk >> 3) & 7;
    } else {
        b = blk / nh; h = blk - b * nh;
    }
    const int row0 = blockIdx.z * ROWS;

    const int tid = threadIdx.x, wid = tid >> 6, lane = tid & 63;
    const int fr = lane & 15;
    const int g4 = (lane >> 4) << 2;
    const int fk = (lane >> 4) << 3;

    const short* Qh = Qp + h * 768;
    const short* Kb = Kp + (long)b * sK + h * khs;
    const short* Vb = VTp + (long)b * sVT + (long)h * vhs * ldv;

    const int wmA = wid * (RI * 16);
    floatx4 accS[RI][NTT];
    #pragma unroll
    for (int i = 0; i < RI; ++i)
        #pragma unroll
        for (int j = 0; j < NTT; ++j) accS[i][j] = (floatx4){0.f, 0.f, 0.f, 0.f};

    const short* qrow[RI];
    #pragma unroll
    for (int i = 0; i < RI; ++i)
        qrow[i] = Qh + (long)(row0 + wmA + i * 16 + fr) * ldq + fk;

    const int rowg  = (wid << 3) + (lane >> 3);
    const int slotx = ((lane & 7) ^ ((lane >> 3) & 7)) << 3;
    const short* ksrc = Kb + (long)rowg * ldk + slotx;
    short* kdst0 = lds + (wid << 9);

    for (int t = 0; t < 12; ++t) {
        const int kt = t << 6;
        #pragma unroll
        for (int p = 0; p < KP / 32; ++p)
            gld_lds16(ksrc + ((long)(p << 5) * ldk + kt), kdst0 + (p << 11));
        __syncthreads();
        #pragma unroll
        for (int kkb = 0; kkb < 2; ++kkb) {
            const int kk = kkb << 5;
            short8 aF[RI];
            #pragma unroll
            for (int i = 0; i < RI; ++i)
                aF[i] = *(const short8*)(qrow[i] + kt + kk);
            const int sl = ((((kk >> 3) + (lane >> 4)) ^ (fr & 7)) << 3);
            #pragma unroll
            for (int j = 0; j < NTT; ++j) {
                const short8 bF = *(const short8*)(lds + ((j << 4) + fr) * 64 + sl);
                #pragma unroll
                for (int i = 0; i < RI; ++i)
                    accS[i][j] = __builtin_amdgcn_mfma_f32_16x16x32_bf16(aF[i], bF, accS[i][j], 0, 0, 0);
            }
        }
        __syncthreads();
    }

    float inv[RI][4];
    #pragma unroll
    for (int i = 0; i < RI; ++i) {
        #pragma unroll
        for (int r = 0; r < 4; ++r) {
            float m = -1e30f;
            #pragma unroll
            for (int j = 0; j < NTT; ++j) {
                const int col = j * 16 + fr;
                if (col < nt) m = fmaxf(m, accS[i][j][r]);
            }
            #pragma unroll
            for (int off = 1; off < 16; off <<= 1) m = fmaxf(m, __shfl_xor(m, off));
            float s = 0.0f;
            #pragma unroll
            for (int j = 0; j < NTT; ++j) {
                const int col = j * 16 + fr;
                float e = (col < nt) ? __expf((accS[i][j][r] - m) * scale) : 0.0f;
                accS[i][j][r] = e;
                s += e;
            }
            #pragma unroll
            for (int off = 1; off < 16; off <<= 1) s += __shfl_xor(s, off);
            inv[i][r] = 1.0f / s;
        }
    }

    #pragma unroll
    for (int i = 0; i < RI; ++i)
        #pragma unroll
        for (int j = 0; j < NTT; ++j)
            #pragma unroll
            for (int r = 0; r < 4; ++r)
                Pl[wmA + i * 16 + g4 + r][j * 16 + fr] = f2bf(accS[i][j][r] * inv[i][r]);
    __syncthreads();

    constexpr int WGN = (RI == 2) ? 2 : 4;
    constexpr int NSTEP = WGN * 64;
    const int wm2 = (wid / WGN) << 6;
    const int wn2 = (wid % WGN) << 6;
    short* Cb = Cp + (long)b * sC + h * 768;

    const int chunk = 768 / gridDim.y;
    const int n0b = blockIdx.y * chunk;
    for (int n0 = n0b; n0 < n0b + chunk; n0 += NSTEP) {
        floatx4 acc2[4][4];
        #pragma unroll
        for (int i = 0; i < 4; ++i)
            #pragma unroll
            for (int j = 0; j < 4; ++j) acc2[i][j] = (floatx4){0.f, 0.f, 0.f, 0.f};
        #pragma unroll
        for (int kk = 0; kk < KP; kk += 32) {
            short8 aF[4], bF[4];
            #pragma unroll
            for (int i = 0; i < 4; ++i)
                aF[i] = *(const short8*)(&Pl[wm2 + i * 16 + fr][kk + fk]);
            #pragma unroll
            for (int j = 0; j < 4; ++j)
                bF[j] = *(const short8*)(Vb + (long)(n0 + wn2 + j * 16 + fr) * ldv + kk + fk);
            #pragma unroll
            for (int i = 0; i < 4; ++i)
                #pragma unroll
                for (int j = 0; j < 4; ++j)
                    acc2[i][j] = __builtin_amdgcn_mfma_f32_16x16x32_bf16(aF[i], bF[j], acc2[i][j], 0, 0, 0);
        }
        #pragma unroll
        for (int j = 0; j < 4; ++j) {
            const int col = n0 + wn2 + (j << 4) + fr;
            #pragma unroll
            for (int i = 0; i < 4; ++i) {
                #pragma unroll
                for (int r = 0; r < 4; ++r) {
                    const int row = row0 + wm2 + (i << 4) + g4 + r;
                    if (row < 100)
                        Cb[(long)row * ldc + col] = f2bf(acc2[i][j][r]);
                }
            }
        }
    }
}

// ---------------------------------------------------------------------------
// 512-thread fused cross-attention: block = (b, h), 128 Q-rows, 8 waves.
// ---------------------------------------------------------------------------
template<int NTT>
__global__ __launch_bounds__(512)
void attn8_kernel(const short* __restrict__ Qp, const short* __restrict__ Kp,
                  const short* __restrict__ VTp, short* __restrict__ Cp,
                  int nt, int ldq, int ldk, int ldv, int ldc,
                  long sK, long sVT, long sC, float scale)
{
    constexpr int KP   = NTT * 16;        // 224
    constexpr int PLD  = KP + 8;          // 232
    constexpr int KBUF = KP * 64;
    constexpr int P_SH = 128 * PLD;
    constexpr int LDS_SH = (2 * KBUF > P_SH) ? 2 * KBUF : P_SH;
    __shared__ __align__(16) short lds[LDS_SH];
    short (*Pl)[PLD] = reinterpret_cast<short (*)[PLD]>(lds);

    const int blk = blockIdx.x;
    const int b = ((blk & 7) << 3) + (blk >> 6);
    const int h = (blk >> 3) & 7;

    const int tid = threadIdx.x, wid = tid >> 6, lane = tid & 63;
    const int fr = lane & 15;
    const int g4 = (lane >> 4) << 2;
    const int fk = (lane >> 4) << 3;

    const short* Qh = Qp + h * 768;
    const short* Kb = Kp + (long)b * sK;
    const short* Vb = VTp + (long)b * sVT;

    const int wmA = wid << 4;
    floatx4 accS[NTT];
    #pragma unroll
    for (int j = 0; j < NTT; ++j) accS[j] = (floatx4){0.f, 0.f, 0.f, 0.f};

    const short* qrow = Qh + (long)(wmA + fr) * ldq + fk;

    const int rowg  = (wid << 3) + (lane >> 3);
    const int slotx = ((lane & 7) ^ ((lane >> 3) & 7)) << 3;
    const short* ksrc = Kb + (long)rowg * ldk + slotx;

    auto stageK = [&](int buf, int kt) {
        short* dst = lds + buf * KBUF + (wid << 9);
        #pragma unroll
        for (int p = 0; p < 4; ++p)
            if (p < 3 || wid < 4)
                gld_lds16(ksrc + ((long)(p << 6) * ldk + kt), dst + (p << 12));
    };

    stageK(0, 0);
    __syncthreads();
    for (int t = 0; t < 12; ++t) {
        const int cur = t & 1;
        if (t < 11) stageK(cur ^ 1, (t + 1) << 6);
        const int kt = t << 6;
        const short* kb = lds + cur * KBUF;
        #pragma unroll
        for (int kkb = 0; kkb < 2; ++kkb) {
            const int kk = kkb << 5;
            const short8 aF = *(const short8*)(qrow + kt + kk);
            const int sl = ((((kk >> 3) + (lane >> 4)) ^ (fr & 7)) << 3);
            #pragma unroll
            for (int j = 0; j < NTT; ++j) {
                const short8 bF = *(const short8*)(kb + ((j << 4) + fr) * 64 + sl);
                accS[j] = __builtin_amdgcn_mfma_f32_16x16x32_bf16(aF, bF, accS[j], 0, 0, 0);
            }
        }
        __syncthreads();
    }

    float inv_[4];
    #pragma unroll
    for (int r = 0; r < 4; ++r) {
        float m = -1e30f;
        #pragma unroll
        for (int j = 0; j < NTT; ++j) {
            const int col = j * 16 + fr;
            if (col < nt) m = fmaxf(m, accS[j][r]);
        }
        #pragma unroll
        for (int off = 1; off < 16; off <<= 1) m = fmaxf(m, __shfl_xor(m, off));
        float s = 0.0f;
        #pragma unroll
        for (int j = 0; j < NTT; ++j) {
            const int col = j * 16 + fr;
            float e = (col < nt) ? __expf((accS[j][r] - m) * scale) : 0.0f;
            accS[j][r] = e;
            s += e;
        }
        #pragma unroll
        for (int off = 1; off < 16; off <<= 1) s += __shfl_xor(s, off);
        inv_[r] = 1.0f / s;
    }

    #pragma unroll
    for (int j = 0; j < NTT; ++j)
        #pragma unroll
        for (int r = 0; r < 4; ++r)
            Pl[wmA + g4 + r][j * 16 + fr] = f2bf(accS[j][r] * inv_[r]);
    __syncthreads();

    const int wm2 = (wid >> 2) << 6;
    const int wn2 = (wid & 3) << 6;
    short* Cb = Cp + (long)b * sC + h * 768;

    for (int n0 = 0; n0 < 768; n0 += 256) {
        #pragma unroll
        for (int jh = 0; jh < 2; ++jh) {
            floatx4 acc2[4][2];
            #pragma unroll
            for (int i = 0; i < 4; ++i)
                #pragma unroll
                for (int j = 0; j < 2; ++j) acc2[i][j] = (floatx4){0.f, 0.f, 0.f, 0.f};
            #pragma unroll
            for (int kk = 0; kk < KP; kk += 32) {
                short8 aF[4], bF[2];
                #pragma unroll
                for (int i = 0; i < 4; ++i)
                    aF[i] = *(const short8*)(&Pl[wm2 + i * 16 + fr][kk + fk]);
                #pragma unroll
                for (int j = 0; j < 2; ++j)
                    bF[j] = *(const short8*)(Vb + (long)(n0 + wn2 + (jh * 2 + j) * 16 + fr) * ldv + kk + fk);
                #pragma unroll
                for (int i = 0; i < 4; ++i)
                    #pragma unroll
                    for (int j = 0; j < 2; ++j)
                        acc2[i][j] = __builtin_amdgcn_mfma_f32_16x16x32_bf16(aF[i], bF[j], acc2[i][j], 0, 0, 0);
            }
            #pragma unroll
            for (int j = 0; j < 2; ++j) {
                const int col = n0 + wn2 + ((jh * 2 + j) << 4) + fr;
                #pragma unroll
                for (int i = 0; i < 4; ++i) {
                    #pragma unroll
                    for (int r = 0; r < 4; ++r) {
                        const int row = wm2 + (i << 4) + g4 + r;
                        if (row < 100)
                            Cb[(long)row * ldc + col] = f2bf(acc2[i][j][r]);
                    }
                }
            }
        }
    }
}

// ---------------------------------------------------------------------------
// Batched transpose: in [R,Cc] (f32 or bf16) -> out [Cc][ldout] bf16.
// ---------------------------------------------------------------------------
template<bool IN_F32>
__global__ __launch_bounds__(256)
void transpose_kernel(const void* __restrict__ inp, short* __restrict__ outp,
                      int R, int Cc, int ldout)
{
    __shared__ short tile[64][65];
    const long in_off = (long)blockIdx.z * R * Cc;
    const long out_off = (long)blockIdx.z * Cc * ldout;
    const int bx = blockIdx.x << 6;
    const int by = blockIdx.y << 6;
    const int tx = threadIdx.x & 63, ty = threadIdx.x >> 6;
    #pragma unroll
    for (int i = ty; i < 64; i += 4) {
        const int r = by + i, c = bx + tx;
        short v = 0;
        if (r < R && c < Cc) {
            if constexpr (IN_F32) v = f2bf(((const float*)inp)[in_off + (long)r * Cc + c]);
            else                  v = ((const short*)inp)[in_off + (long)r * Cc + c];
        }
        tile[i][tx] = v;
    }
    __syncthreads();
    #pragma unroll
    for (int i = ty; i < 64; i += 4) {
        const int c = bx + i, r = by + tx;
        if (c < Cc && r < ldout) outp[out_off + (long)c * ldout + r] = tile[tx][i];
    }
}

// ---------------------------------------------------------------------------
// Split-K reduce + bias + residual (+ optional LayerNorm).
// ---------------------------------------------------------------------------
template<bool DO_LN, bool PBF16>
__global__ __launch_bounds__(192)
void reduce_kernel(const void* __restrict__ part, int nsplit, long pstride,
                   const float* __restrict__ resid, int rmod,
                   const float* __restrict__ bias,
                   const float* __restrict__ g, const float* __restrict__ bvec,
                   float* __restrict__ hout, short* __restrict__ hnout)
{
    const long row = blockIdx.x;
    const int t = threadIdx.x;
    const int c = t << 2;
    const float* rr = resid + (long)(row % rmod) * 768;
    float4 v = *(const float4*)(rr + c);
    const float4 bb = *(const float4*)(bias + c);
    v.x += bb.x; v.y += bb.y; v.z += bb.z; v.w += bb.w;
    for (int s = 0; s < nsplit; ++s) {
        const long idx = (long)s * pstride + row * 768 + c;
        if constexpr (PBF16) {
            const short4b p = *(const short4b*)((const short*)part + idx);
            v.x += bf2f(p[0]); v.y += bf2f(p[1]); v.z += bf2f(p[2]); v.w += bf2f(p[3]);
        } else {
            const float4 p = *(const float4*)((const float*)part + idx);
            v.x += p.x; v.y += p.y; v.z += p.z; v.w += p.w;
        }
    }
    *(float4*)(hout + row * 768 + c) = v;
    if constexpr (DO_LN) {
        float s  = v.x + v.y + v.z + v.w;
        float sq = v.x * v.x + v.y * v.y + v.z * v.z + v.w * v.w;
        #pragma unroll
        for (int off = 32; off; off >>= 1) {
            s  += __shfl_xor(s, off);
            sq += __shfl_xor(sq, off);
        }
        __shared__ float ss[4], ssq[4];
        const int wv = t >> 6;
        if ((t & 63) == 0) { ss[wv] = s; ssq[wv] = sq; }
        __syncthreads();
        s  = ss[0] + ss[1] + ss[2];
        sq = ssq[0] + ssq[1] + ssq[2];
        const float mean = s * (1.0f / 768.0f);
        const float var  = sq * (1.0f / 768.0f) - mean * mean;
        const float rstd = rsqrtf(var + 1e-5f);
        const float4 gv = *(const float4*)(g + c);
        const float4 bv = *(const float4*)(bvec + c);
        short4b o;
        o[0] = f2bf((v.x - mean) * rstd * gv.x + bv.x);
        o[1] = f2bf((v.y - mean) * rstd * gv.y + bv.y);
        o[2] = f2bf((v.z - mean) * rstd * gv.z + bv.z);
        o[3] = f2bf((v.w - mean) * rstd * gv.w + bv.w);
        *(short4b*)(hnout + row * 768 + c) = o;
    }
}

// ---------------------------------------------------------------------------
__global__ __launch_bounds__(192)
void reducen_kernel(const short* __restrict__ part, int nsplit, long pstride,
                    short* __restrict__ out, int grps)
{
    const int blk = blockIdx.x;
    const int row = blk / grps, grp = blk - row * grps;
    const long base = (long)row * grps * 768 + grp * 768 + (threadIdx.x << 2);
    float4 v = {0.f, 0.f, 0.f, 0.f};
    for (int s = 0; s < nsplit; ++s) {
        const short4b p = *(const short4b*)(part + (long)s * pstride + base);
        v.x += bf2f(p[0]); v.y += bf2f(p[1]); v.z += bf2f(p[2]); v.w += bf2f(p[3]);
    }
    short4b o;
    o[0] = f2bf(v.x); o[1] = f2bf(v.y); o[2] = f2bf(v.z); o[3] = f2bf(v.w);
    *(short4b*)(out + base) = o;
}

// ---------------------------------------------------------------------------
__global__ __launch_bounds__(64)
void groupfc_kernel(const float* __restrict__ h, const float* __restrict__ dp,
                    const float* __restrict__ bias, float* __restrict__ out)
{
    const int bg = blockIdx.x;
    const int g = bg % 100;
    const int t = threadIdx.x;
    const float* hr = h + (long)bg * 768;
    const float* d = dp + (long)g * 7680;
    float acc[10];
    #pragma unroll
    for (int f = 0; f < 10; ++f) acc[f] = 0.0f;
    for (int k = t; k < 768; k += 64) {
        const float hv = hr[k];
        const float* dr = d + k * 10;
        #pragma unroll
        for (int f = 0; f < 10; ++f) acc[f] += hv * dr[f];
    }
    #pragma unroll
    for (int f = 0; f < 10; ++f) {
        #pragma unroll
        for (int off = 32; off; off >>= 1) acc[f] += __shfl_xor(acc[f], off);
    }
    if (t == 0) {
        const int b = bg / 100;
        #pragma unroll
        for (int f = 0; f < 10; ++f)
            out[(long)b * 1000 + g * 10 + f] = acc[f] + bias[g * 10 + f];
    }
}

// ---------------------------------------------------------------------------
extern "C" void kernel_launch(void* const* d_in, const int* in_sizes, int n_in,
                              void* d_out, int out_size, void* d_ws, size_t ws_size,
                              hipStream_t stream)
{
    const float* x       = (const float*)d_in[0];
    const float* W_embed = (const float*)d_in[1];
    const float* b_embed = (const float*)d_in[2];
    const float* qe      = (const float*)d_in[3];
    const float* ln1_g   = (const float*)d_in[4];
    const float* ln1_b   = (const float*)d_in[5];
    const float* Wq_s    = (const float*)d_in[6];
    const float* Wk_s    = (const float*)d_in[7];
    const float* Wv_s    = (const float*)d_in[8];
    const float* Wo_s    = (const float*)d_in[9];
    const float* bo_s    = (const float*)d_in[10];
    const float* ln2_g   = (const float*)d_in[11];
    const float* ln2_b   = (const float*)d_in[12];
    const float* Wq_c    = (const float*)d_in[13];
    const float* Wk_c    = (const float*)d_in[14];
    const float* Wv_c    = (const float*)d_in[15];
    const float* Wo_c    = (const float*)d_in[16];
    const float* bo_c    = (const float*)d_in[17];
    const float* ln3_g   = (const float*)d_in[18];
    const float* ln3_b   = (const float*)d_in[19];
    const float* W1      = (const float*)d_in[20];
    const float* b1      = (const float*)d_in[21];
    const float* W2      = (const float*)d_in[22];
    const float* b2      = (const float*)d_in[23];
    const float* dpool   = (const float*)d_in[24];
    const float* dbias   = (const float*)d_in[25];

    char* base = (char*)d_ws;
    size_t off = 0;
    auto alloc = [&](size_t bytes) -> void* {
        void* p = base + off;
        off += (bytes + 255) & ~(size_t)255;
        return p;
    };
    short* ek    = (short*)alloc(12544L * 768 * 2);      // emb bf16 [12544][768]
    short* ekT   = (short*)alloc(64L * 768 * 256 * 2);   // emb^T [b][768][256] zero-pad
    short* big   = (short*)alloc(6400L * 6144 * 2);      // xT, then ctx_c
    char*  shr   = (char*) alloc(4L * 6400 * 768 * 4);   // bf16 split-K planes
    float* h2    = (float*)alloc(6400L * 768 * 4);       // residual stream (b-dep)
    short* hn3   = (short*)alloc(6400L * 768 * 2);
    short* t1    = (short*)alloc(6400L * 2048 * 2);
    short* WembT = (short*)alloc(768L * 2048 * 2);
    short* W1T   = (short*)alloc(2048L * 768 * 2);
    short* W2T   = (short*)alloc(768L * 2048 * 2);
    short* WqkTc = (short*)alloc(6144L * 768 * 2);       // [h][768][768] planes
    short* WvoTc = (short*)alloc(768L * 6144 * 2);
    short* WoTc  = (short*)alloc(768L * 6144 * 2);       // Wo_c^T bf16
    short* WqsT  = (short*)alloc(6144L * 768 * 2);       // consecutive: WqsT/WksT/WvsT
    short* WksT  = (short*)alloc(6144L * 768 * 2);
    short* WvsT  = (short*)alloc(6144L * 768 * 2);
    short* WosT  = (short*)alloc(768L * 6144 * 2);
    short* hn1   = (short*)alloc(128L * 768 * 2);        // pad rows stale (finite)
    short* q_s   = (short*)alloc(128L * 6144 * 2);       // consecutive: q_s/k_s/v_s
    short* k_s   = (short*)alloc(128L * 6144 * 2);
    short* v_s   = (short*)alloc(128L * 6144 * 2);
    short* ctx_s = (short*)alloc(128L * 6144 * 2);
    short* v_sT  = (short*)alloc(6144L * 128 * 2);       // zero-pad cols >= 100
    short* qt_c  = (short*)alloc(128L * 6144 * 2);
    short* qtP   = (short*)alloc(4L * 100 * 6144 * 2);   // qt split-K partials bf16
    float* partS = (float*)alloc(8L * 100 * 768 * 4);
    float* h1    = (float*)alloc(128L * 768 * 4);
    short* hn2   = (short*)alloc(128L * 768 * 2);
    (void)ws_size; (void)in_sizes; (void)n_in; (void)out_size;

    short* partCb = (short*)shr;                         // [8][6400][768] bf16

    const float scale = 0.03608439182435161f;  // 768^-0.5

    // ================= merged prep (9 transposes + x + LN1) =================
    short* xT = big;  // [12544][2048] bf16
    prep_kernel<<<dim3(15204), 256, 0, stream>>>(
        W_embed, W1, W2, Wo_c, Wq_s, Wk_s, Wv_s, Wo_s,
        x, qe, ln1_g, ln1_b,
        WembT, W1T, W2T, WoTc, WqsT, WksT, WvsT, WosT, xT, hn1);

    // ---- combined cross weights (A/B read f32 inputs directly) ----
    gemm_kernel<0, true, 128, 1, 1><<<dim3(6, 6, 8), 256, 0, stream>>>(
        Wk_c, Wq_c, nullptr, nullptr, 1, WqkTc,
        768, 768, 768, 768, 768, 6144, 6144, 768, 8,
        0L, 768L, 0L, 768L, 0L, 589824L, 1.0f);
    gemm_kernel<0, true, 128, 0, 1><<<dim3(6, 6, 8), 256, 0, stream>>>(
        WoTc, Wv_c, nullptr, nullptr, 1, WvoTc,
        768, 768, 768, 768, 768, 6144, 6144, 6144, 8,
        0L, 768L, 0L, 768L, 0L, 768L, 1.0f);

    // ================= embed =================
    gemm_kernel<1, true, 64><<<dim3(6, 196, 1), 256, 0, stream>>>(
        xT, WembT, b_embed, nullptr, 1, ek,
        12544, 768, 2048, 12544, 768, 2048, 2048, 768, 1,
        0L, 0L, 0L, 0L, 0L, 0L, 1.0f);
    transpose_kernel<false><<<dim3(12, 4, 64), 256, 0, stream>>>(ek, ekT, 196, 768, 256);

    // ================= self-attention (batch-invariant, 100 rows) ==========
    // q/k/v projections in ONE batched launch (bf16 BT weights, consecutive)
    gemm_kernel<0, true, 128><<<dim3(48, 1, 3), 256, 0, stream>>>(
        hn1, WqsT, nullptr, nullptr, 1, q_s,
        100, 6144, 768, 128, 6144, 768, 768, 6144, 1,
        0L, 0L, 4718592L, 0L, 786432L, 0L, 1.0f);
    transpose_kernel<false><<<dim3(96, 2, 1), 256, 0, stream>>>(v_s, v_sT, 100, 6144, 128);
    attn_kernel<8, 2><<<dim3(8, 6, 1), 256, 0, stream>>>(
        q_s, k_s, v_sT, ctx_s,
        100, 8, 6144, 6144, 128, 6144,
        768, 768, 0L, 0L, 0L, scale);
    gemm_kernel<0, false, 128><<<dim3(6, 1, 8), 256, 0, stream>>>(
        ctx_s, WosT, nullptr, nullptr, 1, partS,
        100, 768, 768, 128, 768, 6144, 6144, 768, 8,
        0L, 768L, 0L, 768L, 0L, 76800L, 1.0f);
    reduce_kernel<true, false><<<dim3(100), 192, 0, stream>>>(
        partS, 8, 76800L, qe, 100, bo_s, ln2_g, ln2_b, h1, hn2);

    // ================= cross-attention =================
    gemm_kernel<0, true, 128><<<dim3(48, 1, 4), 256, 0, stream>>>(
        hn2, WqkTc, nullptr, nullptr, 1, qtP,
        100, 6144, 192, 128, 6144, 768, 768, 6144, 4,
        0L, 192L, 0L, 192L, 0L, 614400L, 1.0f);
    reducen_kernel<<<dim3(800), 192, 0, stream>>>(qtP, 4, 614400L, qt_c, 8);
    attn8_kernel<14><<<dim3(512), 512, 0, stream>>>(
        qt_c, ek, ekT, big,
        196, 6144, 768, 256, 6144,
        150528L, 196608L, 614400L, scale);
    gemm_kernel<0, true, 128><<<dim3(6, 50, 8), 256, 0, stream>>>(
        big, WvoTc, nullptr, nullptr, 1, partCb,
        6400, 768, 768, 6400, 768, 6144, 6144, 768, 8,
        0L, 768L, 0L, 768L, 0L, 4915200L, 1.0f);
    reduce_kernel<true, true><<<dim3(6400), 192, 0, stream>>>(
        partCb, 8, 4915200L, h1, 100, bo_c, ln3_g, ln3_b, h2, hn3);

    // ================= MLP =================
    gemm_kernel<2, true, 64><<<dim3(16, 100, 1), 256, 0, stream>>>(
        hn3, W1T, b1, nullptr, 1, t1,
        6400, 2048, 768, 6400, 2048, 768, 768, 2048, 1, 0,0,0,0,0,0, 1.0f);
    gemm_kernel<0, true, 128><<<dim3(6, 50, 4), 256, 0, stream>>>(
        t1, W2T, nullptr, nullptr, 1, partCb,
        6400, 768, 512, 6400, 768, 2048, 2048, 768, 4,
        0L, 512L, 0L, 512L, 0L, 4915200L, 1.0f);
    reduce_kernel<false, true><<<dim3(6400), 192, 0, stream>>>(
        partCb, 4, 4915200L, h2, 6400, b2, nullptr, nullptr, h2, nullptr);

    // ================= GroupFC =================
    groupfc_kernel<<<dim3(6400), 64, 0, stream>>>(h2, dpool, dbias, (float*)d_out);
}

// Round 19
// 727.523 us; speedup vs baseline: 1.4796x; 1.3148x over previous
//
#include <hip/hip_runtime.h>
#include <hip/hip_bf16.h>

// ---------------------------------------------------------------------------
// MLDecoder forward on MI355X (gfx950).  Round 19:
//  - FULL revert to round-16 dataflow: CQ/CK/CV casts back in prep, combine
//    GEMMs on the bf16 global_load_lds fast path.  Round-18 post-mortem:
//    manual f32 staging (AM1/BM1) cannot pipeline across the barrier (ds_write
//    depends on load), so at 288 blocks = 1.1/CU each combine GEMM was
//    ~100 us.  Rule: f32 operands only where blocks/CU >= 4.
//  - NEW: prep transposes vectorized (float4 loads -> LDS [64][68] bf16 tile
//    -> short4b column stores); 16 scalar loads+stores/thread -> 4+4 vector.
// ---------------------------------------------------------------------------

typedef __attribute__((ext_vector_type(8))) short short8;   // 8 bf16
typedef __attribute__((ext_vector_type(4))) short short4b;  // 4 bf16
typedef __attribute__((ext_vector_type(4))) float floatx4;

#define DEVI static __device__ __forceinline__

DEVI short f2bf(float f) {
    union { __hip_bfloat16 h; short s; } u;
    u.h = __float2bfloat16(f);
    return u.s;
}

DEVI float bf2f(short s) {
    union { float f; unsigned u; } v;
    v.u = ((unsigned)(unsigned short)s) << 16;
    return v.f;
}

DEVI void gld_lds16(const void* g, void* l) {
    __builtin_amdgcn_global_load_lds(
        (const __attribute__((address_space(1))) void*)g,
        (__attribute__((address_space(3))) void*)l, 16, 0, 0);
}

// ---------------------------------------------------------------------------
// prep_kernel: all input-only prep in one launch (round-16 ladder, vectorized
// transposes).
//   blocks [0,384)      W_embed [2048x768]  -> WembT (ld 2048)
//   blocks [384,768)    W1      [768x2048]  -> W1T   (ld 768)
//   blocks [768,1152)   W2      [2048x768]  -> W2T   (ld 2048)
//   blocks [1152,2304)  Wq_s    [768x6144]  -> WqsT  (ld 768)
//   blocks [2304,3456)  Wk_s                -> WksT
//   blocks [3456,4608)  Wv_s                -> WvsT
//   blocks [4608,5760)  Wo_s    [6144x768]  -> WosT  (ld 6144)
//   blocks [5760,6912)  Wo_c    [6144x768]  -> WoTc  (ld 6144)
//   blocks [6912,20736) casts Wq_c/Wk_c/Wv_c -> CQ/CK/CV (bf16)
//   blocks [20736,28928) x [64][2048][196]  -> xT [64][196][2048] bf16
//   blocks [28928,29028) LN1(query_embed)   -> hn1 (100 rows)
// All transpose jobs have R % 64 == 0 and ldo == R; only x has C % 64 != 0.
// ---------------------------------------------------------------------------
__global__ __launch_bounds__(256)
void prep_kernel(const float* __restrict__ W_embed, const float* __restrict__ W1,
                 const float* __restrict__ W2, const float* __restrict__ Wq_s,
                 const float* __restrict__ Wk_s, const float* __restrict__ Wv_s,
                 const float* __restrict__ Wo_s, const float* __restrict__ Wo_c,
                 const float* __restrict__ Wq_c, const float* __restrict__ Wk_c,
                 const float* __restrict__ Wv_c, const float* __restrict__ x,
                 const float* __restrict__ qe, const float* __restrict__ ln1_g,
                 const float* __restrict__ ln1_b,
                 short* __restrict__ WembT, short* __restrict__ W1T,
                 short* __restrict__ W2T, short* __restrict__ WqsT,
                 short* __restrict__ WksT, short* __restrict__ WvsT,
                 short* __restrict__ WosT, short* __restrict__ WoTc,
                 short* __restrict__ CQ, short* __restrict__ CK,
                 short* __restrict__ CV, short* __restrict__ xT,
                 short* __restrict__ hn1)
{
    const int bid = blockIdx.x;
    const int t = threadIdx.x;

    // ---------------- cast jobs ----------------
    if (bid >= 6912 && bid < 20736) {
        int lb = bid - 6912;
        const float* in; short* out;
        if (lb < 4608)       { in = Wq_c; out = CQ; }
        else if (lb < 9216)  { in = Wk_c; out = CK; lb -= 4608; }
        else                 { in = Wv_c; out = CV; lb -= 9216; }
        const long i = (long)lb * 256 + t;
        const float4 v = ((const float4*)in)[i];
        short4b s; s[0] = f2bf(v.x); s[1] = f2bf(v.y); s[2] = f2bf(v.z); s[3] = f2bf(v.w);
        ((short4b*)out)[i] = s;
        return;
    }

    __shared__ __align__(16) short tile[64][68];

    // ---------------- LN1 job ----------------
    if (bid >= 28928) {
        const int row = bid - 28928;
        float* ss  = (float*)&tile[0][0];
        float* ssq = ss + 4;
        float4 v = {0.f, 0.f, 0.f, 0.f};
        float s = 0.f, sq = 0.f;
        if (t < 192) {
            v = *(const float4*)(qe + (long)row * 768 + (t << 2));
            s  = v.x + v.y + v.z + v.w;
            sq = v.x * v.x + v.y * v.y + v.z * v.z + v.w * v.w;
            #pragma unroll
            for (int off = 32; off; off >>= 1) {
                s  += __shfl_xor(s, off);
                sq += __shfl_xor(sq, off);
            }
            if ((t & 63) == 0) { ss[t >> 6] = s; ssq[t >> 6] = sq; }
        }
        __syncthreads();
        if (t < 192) {
            s  = ss[0] + ss[1] + ss[2];
            sq = ssq[0] + ssq[1] + ssq[2];
            const float mean = s * (1.0f / 768.0f);
            const float var  = sq * (1.0f / 768.0f) - mean * mean;
            const float rstd = rsqrtf(var + 1e-5f);
            const float4 gv = *(const float4*)(ln1_g + (t << 2));
            const float4 bv = *(const float4*)(ln1_b + (t << 2));
            short4b o;
            o[0] = f2bf((v.x - mean) * rstd * gv.x + bv.x);
            o[1] = f2bf((v.y - mean) * rstd * gv.y + bv.y);
            o[2] = f2bf((v.z - mean) * rstd * gv.z + bv.z);
            o[3] = f2bf((v.w - mean) * rstd * gv.w + bv.w);
            *(short4b*)(hn1 + (long)row * 768 + (t << 2)) = o;
        }
        return;
    }

    // ---------------- transpose jobs (vectorized) ----------------
    const float* in; short* out; int R, C, ldo, bx, by;
    long ioff = 0, ooff = 0;
    if (bid < 384)       { in = W_embed; out = WembT; R = 2048; C = 768;  ldo = 2048; bx = bid % 12;  by = bid / 12; }
    else if (bid < 768)  { const int l = bid - 384;  in = W1;   out = W1T;  R = 768;  C = 2048; ldo = 768;  bx = l % 32; by = l / 32; }
    else if (bid < 1152) { const int l = bid - 768;  in = W2;   out = W2T;  R = 2048; C = 768;  ldo = 2048; bx = l % 12; by = l / 12; }
    else if (bid < 2304) { const int l = bid - 1152; in = Wq_s; out = WqsT; R = 768;  C = 6144; ldo = 768;  bx = l % 96; by = l / 96; }
    else if (bid < 3456) { const int l = bid - 2304; in = Wk_s; out = WksT; R = 768;  C = 6144; ldo = 768;  bx = l % 96; by = l / 96; }
    else if (bid < 4608) { const int l = bid - 3456; in = Wv_s; out = WvsT; R = 768;  C = 6144; ldo = 768;  bx = l % 96; by = l / 96; }
    else if (bid < 5760) { const int l = bid - 4608; in = Wo_s; out = WosT; R = 6144; C = 768;  ldo = 6144; bx = l % 12; by = l / 12; }
    else if (bid < 6912) { const int l = bid - 5760; in = Wo_c; out = WoTc; R = 6144; C = 768;  ldo = 6144; bx = l % 12; by = l / 12; }
    else {  // x transpose: [20736, 28928)
        const int l = bid - 20736;
        const int z = l >> 7, rem = l & 127;
        in = x; out = xT; R = 2048; C = 196; ldo = 2048;
        bx = rem % 4; by = rem / 4;
        ioff = (long)z * 2048 * 196;
        ooff = (long)z * 196 * 2048;
    }

    const int bxo = bx << 6, byo = by << 6;
    const int lr  = t >> 4;             // 0..15
    const int lc4 = (t & 15) << 2;      // 0..60

    // load: 4 passes of float4 (rows always in-range: R % 64 == 0)
    #pragma unroll
    for (int p = 0; p < 4; ++p) {
        const int i = lr + (p << 4);
        const int c = bxo + lc4;
        const long rb = ioff + (long)(byo + i) * C;
        short4b s;
        if (c + 4 <= C) {
            const float4 v = *(const float4*)(in + rb + c);
            s[0] = f2bf(v.x); s[1] = f2bf(v.y); s[2] = f2bf(v.z); s[3] = f2bf(v.w);
        } else {
            #pragma unroll
            for (int j = 0; j < 4; ++j)
                s[j] = (c + j < C) ? f2bf(in[rb + c + j]) : (short)0;
        }
        *(short4b*)(&tile[i][lc4]) = s;
    }
    __syncthreads();
    // store: 4 passes of short4b along transposed rows (out rows = cols of in)
    #pragma unroll
    for (int p = 0; p < 4; ++p) {
        const int ci = lr + (p << 4);
        const int c2 = bxo + ci;
        if (c2 < C) {
            const int r0 = lc4;
            short4b s;
            s[0] = tile[r0][ci]; s[1] = tile[r0 + 1][ci];
            s[2] = tile[r0 + 2][ci]; s[3] = tile[r0 + 3][ci];
            *(short4b*)(out + ooff + (long)c2 * ldo + byo + r0) = s;
        }
    }
}

// ---------------------------------------------------------------------------
// Tiled GEMM:  C[m,n] = act(alpha * sum_k A[m,k]*B[k,n] + bias[n])
//                       + resid[(m % rmod)][n]
// A bf16 row-major [M,K]; B bf16 BT [N,K].  2-phase dbuf K-loop;
// LDS-bounce bf16 epilogue (N % 128 == 0 for OUT_BF16).
// ---------------------------------------------------------------------------
template<int ACT, bool OUT_BF16, int TBM>
__global__ __launch_bounds__(256)
void gemm_kernel(const short* __restrict__ Ap, const short* __restrict__ Bp,
                 const float* __restrict__ bias, const float* __restrict__ resid,
                 int rmod, void* __restrict__ Cp,
                 int M, int N, int K, int Mpad, int Npad,
                 int lda, int ldb, int ldc, int inner_batch,
                 long sA1, long sA2, long sB1, long sB2, long sC1, long sC2,
                 float alpha)
{
    constexpr int BK_ = 64;
    constexpr int MI  = TBM / 32;
    constexpr int ATS = TBM * BK_;
    constexpr int BTS = 128 * BK_;
    __shared__ __align__(16) short lds_all[2 * (ATS + BTS)];

    const int gx = gridDim.x, gy = gridDim.y;
    const long nwg = (long)gx * gy * gridDim.z;
    const long dfl = blockIdx.x + (long)gx * (blockIdx.y + (long)gy * blockIdx.z);
    const long qch = nwg >> 3, rch = nwg & 7;
    const long xcd = dfl & 7, idx = dfl >> 3;
    const long w = (xcd < rch ? xcd * (qch + 1) : rch * (qch + 1) + (xcd - rch) * qch) + idx;
    const int bx = (int)(w % gx);
    const long wt = w / gx;
    const int by = (int)(wt % gy);
    const int bz = (int)(wt / gy);

    const int outer = bz / inner_batch;
    const int inner = bz - outer * inner_batch;
    const long aoff = (long)outer * sA1 + (long)inner * sA2;
    const long boff = (long)outer * sB1 + (long)inner * sB2;
    const long coff = (long)outer * sC1 + (long)inner * sC2;
    const int m0 = by * TBM, n0 = bx * 128;
    const int tid = threadIdx.x;
    const int wid = tid >> 6, lane = tid & 63;
    const int wm = (wid >> 1) * (TBM / 2);
    const int wn = (wid & 1) << 6;
    const int fr = lane & 15;
    const int fk = (lane >> 4) << 3;

    const short* A = Ap + aoff;
    const short* B = Bp + boff;
    const int rowp = tid >> 3;
    const int col8 = (tid & 7) << 3;
    const int wrow = (tid >> 6) << 3;

    const bool fastA0 = (m0 + TBM <= Mpad);
    const bool fastB0 = (n0 + 128 <= Npad);

    auto stage = [&](int buf, int kt) {
        short* As = lds_all + buf * (ATS + BTS);
        short* Bs = As + ATS;
        if (fastA0 && (kt + BK_ <= K)) {
            const short* src = A + (long)(m0 + rowp) * lda + kt + col8;
            const long rstride = (long)lda << 5;
            #pragma unroll
            for (int p = 0; p < TBM / 32; ++p)
                gld_lds16(src + p * rstride, As + ((p << 5) + wrow) * BK_);
        } else {
            #pragma unroll
            for (int i = 0; i < TBM / 32; ++i) {
                const int row = rowp + (i << 5);
                const int gm = m0 + row, gk = kt + col8;
                short8 v;
                if (gm < M && gk + 8 <= K) {
                    v = *(const short8*)(A + (long)gm * lda + gk);
                } else {
                    #pragma unroll
                    for (int j = 0; j < 8; ++j)
                        v[j] = (gm < M && gk + j < K) ? A[(long)gm * lda + gk + j] : (short)0;
                }
                *(short8*)(As + row * BK_ + col8) = v;
            }
        }
        if (fastB0 && (kt + BK_ <= K)) {
            const short* src = B + (long)(n0 + rowp) * ldb + kt + col8;
            const long rstride = (long)ldb << 5;
            #pragma unroll
            for (int p = 0; p < 4; ++p)
                gld_lds16(src + p * rstride, Bs + ((p << 5) + wrow) * BK_);
        } else {
            #pragma unroll
            for (int i = 0; i < 4; ++i) {
                const int row = rowp + (i << 5);
                const int gn = n0 + row, gk = kt + col8;
                short8 v;
                if (gn < N && gk + 8 <= K) {
                    v = *(const short8*)(B + (long)gn * ldb + gk);
                } else {
                    #pragma unroll
                    for (int j = 0; j < 8; ++j)
                        v[j] = (gn < N && gk + j < K) ? B[(long)gn * ldb + gk + j] : (short)0;
                }
                *(short8*)(Bs + row * BK_ + col8) = v;
            }
        }
    };

    floatx4 acc[MI][4] = {};
    const int nk = K / BK_;

    stage(0, 0);
    __syncthreads();
    for (int t = 0; t < nk; ++t) {
        const int cur = t & 1;
        if (t + 1 < nk) stage(cur ^ 1, (t + 1) * BK_);
        const short* As = lds_all + cur * (ATS + BTS);
        const short* Bs = As + ATS;
        #pragma unroll
        for (int kk = 0; kk < BK_; kk += 32) {
            short8 af[MI], bfv[4];
            #pragma unroll
            for (int i = 0; i < MI; ++i)
                af[i] = *(const short8*)(As + (wm + (i << 4) + fr) * BK_ + kk + fk);
            #pragma unroll
            for (int j = 0; j < 4; ++j)
                bfv[j] = *(const short8*)(Bs + (wn + (j << 4) + fr) * BK_ + kk + fk);
            #pragma unroll
            for (int i = 0; i < MI; ++i)
                #pragma unroll
                for (int j = 0; j < 4; ++j)
                    acc[i][j] = __builtin_amdgcn_mfma_f32_16x16x32_bf16(af[i], bfv[j], acc[i][j], 0, 0, 0);
        }
        __syncthreads();
    }

    if constexpr (OUT_BF16) {
        short (*Cl)[128] = reinterpret_cast<short (*)[128]>(lds_all);
        #pragma unroll
        for (int j = 0; j < 4; ++j) {
            const int lcol = wn + (j << 4) + fr;
            const float bv = bias ? bias[n0 + lcol] : 0.0f;
            #pragma unroll
            for (int i = 0; i < MI; ++i) {
                #pragma unroll
                for (int r = 0; r < 4; ++r) {
                    const int lrow = wm + (i << 4) + ((lane >> 4) << 2) + r;
                    float v = acc[i][j][r] * alpha + bv;
                    if constexpr (ACT == 1) v = fmaxf(v, 0.0f);
                    if constexpr (ACT == 2) {
                        v = 0.5f * v * (1.0f + tanhf(0.7978845608028654f * (v + 0.044715f * v * v * v)));
                    }
                    if (resid)
                        v += resid[(long)((m0 + lrow) % rmod) * ldc + n0 + lcol];
                    Cl[lrow][lcol] = f2bf(v);
                }
            }
        }
        __syncthreads();
        const int pr = tid >> 4;
        const int pc = (tid & 15) << 3;
        #pragma unroll
        for (int it = 0; it < TBM / 16; ++it) {
            const int row = (it << 4) + pr;
            const int gm = m0 + row;
            if (gm < M)
                *(short8*)((short*)Cp + coff + (long)gm * ldc + n0 + pc) =
                    *(const short8*)(&Cl[row][pc]);
        }
    } else {
        #pragma unroll
        for (int j = 0; j < 4; ++j) {
            const int col = n0 + wn + (j << 4) + fr;
            if (col >= N) continue;
            const float bv = bias ? bias[col] : 0.0f;
            #pragma unroll
            for (int i = 0; i < MI; ++i) {
                #pragma unroll
                for (int r = 0; r < 4; ++r) {
                    const int row = m0 + wm + (i << 4) + ((lane >> 4) << 2) + r;
                    if (row >= M) continue;
                    float v = acc[i][j][r] * alpha + bv;
                    if constexpr (ACT == 1) v = fmaxf(v, 0.0f);
                    if constexpr (ACT == 2) {
                        v = 0.5f * v * (1.0f + tanhf(0.7978845608028654f * (v + 0.044715f * v * v * v)));
                    }
                    const long ci = coff + (long)row * ldc + col;
                    if (resid) v += resid[(long)(row % rmod) * ldc + col];
                    ((float*)Cp)[ci] = v;
                }
            }
        }
    }
}

// ---------------------------------------------------------------------------
// 256-thread fused attention (self-attn): block = (b,h) x column-slice.
// ---------------------------------------------------------------------------
template<int NTT, int RI>
__global__ __launch_bounds__(256)
void attn_kernel(const short* __restrict__ Qp, const short* __restrict__ Kp,
                 const short* __restrict__ VTp, short* __restrict__ Cp,
                 int nt, int nh,
                 int ldq, int ldk, int ldv, int ldc,
                 int khs, int vhs,
                 long sK, long sVT, long sC,
                 float scale)
{
    constexpr int KP   = NTT * 16;
    constexpr int PLD  = KP + 8;
    constexpr int ROWS = RI * 64;
    constexpr int KS_SH = KP * 64;
    constexpr int P_SH  = ROWS * PLD;
    constexpr int LDS_SH = (KS_SH > P_SH) ? KS_SH : P_SH;
    __shared__ __align__(16) short lds[LDS_SH];
    short (*Pl)[PLD] = reinterpret_cast<short (*)[PLD]>(lds);

    const int blk = blockIdx.x;
    const int nb = gridDim.x / nh;
    int b, h;
    if (nb == 64) {
        b = ((blk & 7) << 3) + (blk >> 6);
        h = (blk >> 3) & 7;
    } else {
        b = blk / nh; h = blk - b * nh;
    }
    const int row0 = blockIdx.z * ROWS;

    const int tid = threadIdx.x, wid = tid >> 6, lane = tid & 63;
    const int fr = lane & 15;
    const int g4 = (lane >> 4) << 2;
    const int fk = (lane >> 4) << 3;

    const short* Qh = Qp + h * 768;
    const short* Kb = Kp + (long)b * sK + h * khs;
    const short* Vb = VTp + (long)b * sVT + (long)h * vhs * ldv;

    const int wmA = wid * (RI * 16);
    floatx4 accS[RI][NTT];
    #pragma unroll
    for (int i = 0; i < RI; ++i)
        #pragma unroll
        for (int j = 0; j < NTT; ++j) accS[i][j] = (floatx4){0.f, 0.f, 0.f, 0.f};

    const short* qrow[RI];
    #pragma unroll
    for (int i = 0; i < RI; ++i)
        qrow[i] = Qh + (long)(row0 + wmA + i * 16 + fr) * ldq + fk;

    const int rowg  = (wid << 3) + (lane >> 3);
    const int slotx = ((lane & 7) ^ ((lane >> 3) & 7)) << 3;
    const short* ksrc = Kb + (long)rowg * ldk + slotx;
    short* kdst0 = lds + (wid << 9);

    for (int t = 0; t < 12; ++t) {
        const int kt = t << 6;
        #pragma unroll
        for (int p = 0; p < KP / 32; ++p)
            gld_lds16(ksrc + ((long)(p << 5) * ldk + kt), kdst0 + (p << 11));
        __syncthreads();
        #pragma unroll
        for (int kkb = 0; kkb < 2; ++kkb) {
            const int kk = kkb << 5;
            short8 aF[RI];
            #pragma unroll
            for (int i = 0; i < RI; ++i)
                aF[i] = *(const short8*)(qrow[i] + kt + kk);
            const int sl = ((((kk >> 3) + (lane >> 4)) ^ (fr & 7)) << 3);
            #pragma unroll
            for (int j = 0; j < NTT; ++j) {
                const short8 bF = *(const short8*)(lds + ((j << 4) + fr) * 64 + sl);
                #pragma unroll
                for (int i = 0; i < RI; ++i)
                    accS[i][j] = __builtin_amdgcn_mfma_f32_16x16x32_bf16(aF[i], bF, accS[i][j], 0, 0, 0);
            }
        }
        __syncthreads();
    }

    float inv[RI][4];
    #pragma unroll
    for (int i = 0; i < RI; ++i) {
        #pragma unroll
        for (int r = 0; r < 4; ++r) {
            float m = -1e30f;
            #pragma unroll
            for (int j = 0; j < NTT; ++j) {
                const int col = j * 16 + fr;
                if (col < nt) m = fmaxf(m, accS[i][j][r]);
            }
            #pragma unroll
            for (int off = 1; off < 16; off <<= 1) m = fmaxf(m, __shfl_xor(m, off));
            float s = 0.0f;
            #pragma unroll
            for (int j = 0; j < NTT; ++j) {
                const int col = j * 16 + fr;
                float e = (col < nt) ? __expf((accS[i][j][r] - m) * scale) : 0.0f;
                accS[i][j][r] = e;
                s += e;
            }
            #pragma unroll
            for (int off = 1; off < 16; off <<= 1) s += __shfl_xor(s, off);
            inv[i][r] = 1.0f / s;
        }
    }

    #pragma unroll
    for (int i = 0; i < RI; ++i)
        #pragma unroll
        for (int j = 0; j < NTT; ++j)
            #pragma unroll
            for (int r = 0; r < 4; ++r)
                Pl[wmA + i * 16 + g4 + r][j * 16 + fr] = f2bf(accS[i][j][r] * inv[i][r]);
    __syncthreads();

    constexpr int WGN = (RI == 2) ? 2 : 4;
    constexpr int NSTEP = WGN * 64;
    const int wm2 = (wid / WGN) << 6;
    const int wn2 = (wid % WGN) << 6;
    short* Cb = Cp + (long)b * sC + h * 768;

    const int chunk = 768 / gridDim.y;
    const int n0b = blockIdx.y * chunk;
    for (int n0 = n0b; n0 < n0b + chunk; n0 += NSTEP) {
        floatx4 acc2[4][4];
        #pragma unroll
        for (int i = 0; i < 4; ++i)
            #pragma unroll
            for (int j = 0; j < 4; ++j) acc2[i][j] = (floatx4){0.f, 0.f, 0.f, 0.f};
        #pragma unroll
        for (int kk = 0; kk < KP; kk += 32) {
            short8 aF[4], bF[4];
            #pragma unroll
            for (int i = 0; i < 4; ++i)
                aF[i] = *(const short8*)(&Pl[wm2 + i * 16 + fr][kk + fk]);
            #pragma unroll
            for (int j = 0; j < 4; ++j)
                bF[j] = *(const short8*)(Vb + (long)(n0 + wn2 + j * 16 + fr) * ldv + kk + fk);
            #pragma unroll
            for (int i = 0; i < 4; ++i)
                #pragma unroll
                for (int j = 0; j < 4; ++j)
                    acc2[i][j] = __builtin_amdgcn_mfma_f32_16x16x32_bf16(aF[i], bF[j], acc2[i][j], 0, 0, 0);
        }
        #pragma unroll
        for (int j = 0; j < 4; ++j) {
            const int col = n0 + wn2 + (j << 4) + fr;
            #pragma unroll
            for (int i = 0; i < 4; ++i) {
                #pragma unroll
                for (int r = 0; r < 4; ++r) {
                    const int row = row0 + wm2 + (i << 4) + g4 + r;
                    if (row < 100)
                        Cb[(long)row * ldc + col] = f2bf(acc2[i][j][r]);
                }
            }
        }
    }
}

// ---------------------------------------------------------------------------
// 512-thread fused cross-attention: block = (b, h), 128 Q-rows, 8 waves.
// ---------------------------------------------------------------------------
template<int NTT>
__global__ __launch_bounds__(512)
void attn8_kernel(const short* __restrict__ Qp, const short* __restrict__ Kp,
                  const short* __restrict__ VTp, short* __restrict__ Cp,
                  int nt, int ldq, int ldk, int ldv, int ldc,
                  long sK, long sVT, long sC, float scale)
{
    constexpr int KP   = NTT * 16;        // 224
    constexpr int PLD  = KP + 8;          // 232
    constexpr int KBUF = KP * 64;
    constexpr int P_SH = 128 * PLD;
    constexpr int LDS_SH = (2 * KBUF > P_SH) ? 2 * KBUF : P_SH;
    __shared__ __align__(16) short lds[LDS_SH];
    short (*Pl)[PLD] = reinterpret_cast<short (*)[PLD]>(lds);

    const int blk = blockIdx.x;
    const int b = ((blk & 7) << 3) + (blk >> 6);
    const int h = (blk >> 3) & 7;

    const int tid = threadIdx.x, wid = tid >> 6, lane = tid & 63;
    const int fr = lane & 15;
    const int g4 = (lane >> 4) << 2;
    const int fk = (lane >> 4) << 3;

    const short* Qh = Qp + h * 768;
    const short* Kb = Kp + (long)b * sK;
    const short* Vb = VTp + (long)b * sVT;

    const int wmA = wid << 4;
    floatx4 accS[NTT];
    #pragma unroll
    for (int j = 0; j < NTT; ++j) accS[j] = (floatx4){0.f, 0.f, 0.f, 0.f};

    const short* qrow = Qh + (long)(wmA + fr) * ldq + fk;

    const int rowg  = (wid << 3) + (lane >> 3);
    const int slotx = ((lane & 7) ^ ((lane >> 3) & 7)) << 3;
    const short* ksrc = Kb + (long)rowg * ldk + slotx;

    auto stageK = [&](int buf, int kt) {
        short* dst = lds + buf * KBUF + (wid << 9);
        #pragma unroll
        for (int p = 0; p < 4; ++p)
            if (p < 3 || wid < 4)
                gld_lds16(ksrc + ((long)(p << 6) * ldk + kt), dst + (p << 12));
    };

    stageK(0, 0);
    __syncthreads();
    for (int t = 0; t < 12; ++t) {
        const int cur = t & 1;
        if (t < 11) stageK(cur ^ 1, (t + 1) << 6);
        const int kt = t << 6;
        const short* kb = lds + cur * KBUF;
        #pragma unroll
        for (int kkb = 0; kkb < 2; ++kkb) {
            const int kk = kkb << 5;
            const short8 aF = *(const short8*)(qrow + kt + kk);
            const int sl = ((((kk >> 3) + (lane >> 4)) ^ (fr & 7)) << 3);
            #pragma unroll
            for (int j = 0; j < NTT; ++j) {
                const short8 bF = *(const short8*)(kb + ((j << 4) + fr) * 64 + sl);
                accS[j] = __builtin_amdgcn_mfma_f32_16x16x32_bf16(aF, bF, accS[j], 0, 0, 0);
            }
        }
        __syncthreads();
    }

    float inv_[4];
    #pragma unroll
    for (int r = 0; r < 4; ++r) {
        float m = -1e30f;
        #pragma unroll
        for (int j = 0; j < NTT; ++j) {
            const int col = j * 16 + fr;
            if (col < nt) m = fmaxf(m, accS[j][r]);
        }
        #pragma unroll
        for (int off = 1; off < 16; off <<= 1) m = fmaxf(m, __shfl_xor(m, off));
        float s = 0.0f;
        #pragma unroll
        for (int j = 0; j < NTT; ++j) {
            const int col = j * 16 + fr;
            float e = (col < nt) ? __expf((accS[j][r] - m) * scale) : 0.0f;
            accS[j][r] = e;
            s += e;
        }
        #pragma unroll
        for (int off = 1; off < 16; off <<= 1) s += __shfl_xor(s, off);
        inv_[r] = 1.0f / s;
    }

    #pragma unroll
    for (int j = 0; j < NTT; ++j)
        #pragma unroll
        for (int r = 0; r < 4; ++r)
            Pl[wmA + g4 + r][j * 16 + fr] = f2bf(accS[j][r] * inv_[r]);
    __syncthreads();

    const int wm2 = (wid >> 2) << 6;
    const int wn2 = (wid & 3) << 6;
    short* Cb = Cp + (long)b * sC + h * 768;

    for (int n0 = 0; n0 < 768; n0 += 256) {
        #pragma unroll
        for (int jh = 0; jh < 2; ++jh) {
            floatx4 acc2[4][2];
            #pragma unroll
            for (int i = 0; i < 4; ++i)
                #pragma unroll
                for (int j = 0; j < 2; ++j) acc2[i][j] = (floatx4){0.f, 0.f, 0.f, 0.f};
            #pragma unroll
            for (int kk = 0; kk < KP; kk += 32) {
                short8 aF[4], bF[2];
                #pragma unroll
                for (int i = 0; i < 4; ++i)
                    aF[i] = *(const short8*)(&Pl[wm2 + i * 16 + fr][kk + fk]);
                #pragma unroll
                for (int j = 0; j < 2; ++j)
                    bF[j] = *(const short8*)(Vb + (long)(n0 + wn2 + (jh * 2 + j) * 16 + fr) * ldv + kk + fk);
                #pragma unroll
                for (int i = 0; i < 4; ++i)
                    #pragma unroll
                    for (int j = 0; j < 2; ++j)
                        acc2[i][j] = __builtin_amdgcn_mfma_f32_16x16x32_bf16(aF[i], bF[j], acc2[i][j], 0, 0, 0);
            }
            #pragma unroll
            for (int j = 0; j < 2; ++j) {
                const int col = n0 + wn2 + ((jh * 2 + j) << 4) + fr;
                #pragma unroll
                for (int i = 0; i < 4; ++i) {
                    #pragma unroll
                    for (int r = 0; r < 4; ++r) {
                        const int row = wm2 + (i << 4) + g4 + r;
                        if (row < 100)
                            Cb[(long)row * ldc + col] = f2bf(acc2[i][j][r]);
                    }
                }
            }
        }
    }
}

// ---------------------------------------------------------------------------
// Batched transpose: in [R,Cc] (f32 or bf16) -> out [Cc][ldout] bf16.
// ---------------------------------------------------------------------------
template<bool IN_F32>
__global__ __launch_bounds__(256)
void transpose_kernel(const void* __restrict__ inp, short* __restrict__ outp,
                      int R, int Cc, int ldout)
{
    __shared__ short tile[64][65];
    const long in_off = (long)blockIdx.z * R * Cc;
    const long out_off = (long)blockIdx.z * Cc * ldout;
    const int bx = blockIdx.x << 6;
    const int by = blockIdx.y << 6;
    const int tx = threadIdx.x & 63, ty = threadIdx.x >> 6;
    #pragma unroll
    for (int i = ty; i < 64; i += 4) {
        const int r = by + i, c = bx + tx;
        short v = 0;
        if (r < R && c < Cc) {
            if constexpr (IN_F32) v = f2bf(((const float*)inp)[in_off + (long)r * Cc + c]);
            else                  v = ((const short*)inp)[in_off + (long)r * Cc + c];
        }
        tile[i][tx] = v;
    }
    __syncthreads();
    #pragma unroll
    for (int i = ty; i < 64; i += 4) {
        const int c = bx + i, r = by + tx;
        if (c < Cc && r < ldout) outp[out_off + (long)c * ldout + r] = tile[tx][i];
    }
}

// ---------------------------------------------------------------------------
// Split-K reduce + bias + residual (+ optional LayerNorm).
// ---------------------------------------------------------------------------
template<bool DO_LN, bool PBF16>
__global__ __launch_bounds__(192)
void reduce_kernel(const void* __restrict__ part, int nsplit, long pstride,
                   const float* __restrict__ resid, int rmod,
                   const float* __restrict__ bias,
                   const float* __restrict__ g, const float* __restrict__ bvec,
                   float* __restrict__ hout, short* __restrict__ hnout)
{
    const long row = blockIdx.x;
    const int t = threadIdx.x;
    const int c = t << 2;
    const float* rr = resid + (long)(row % rmod) * 768;
    float4 v = *(const float4*)(rr + c);
    const float4 bb = *(const float4*)(bias + c);
    v.x += bb.x; v.y += bb.y; v.z += bb.z; v.w += bb.w;
    for (int s = 0; s < nsplit; ++s) {
        const long idx = (long)s * pstride + row * 768 + c;
        if constexpr (PBF16) {
            const short4b p = *(const short4b*)((const short*)part + idx);
            v.x += bf2f(p[0]); v.y += bf2f(p[1]); v.z += bf2f(p[2]); v.w += bf2f(p[3]);
        } else {
            const float4 p = *(const float4*)((const float*)part + idx);
            v.x += p.x; v.y += p.y; v.z += p.z; v.w += p.w;
        }
    }
    *(float4*)(hout + row * 768 + c) = v;
    if constexpr (DO_LN) {
        float s  = v.x + v.y + v.z + v.w;
        float sq = v.x * v.x + v.y * v.y + v.z * v.z + v.w * v.w;
        #pragma unroll
        for (int off = 32; off; off >>= 1) {
            s  += __shfl_xor(s, off);
            sq += __shfl_xor(sq, off);
        }
        __shared__ float ss[4], ssq[4];
        const int wv = t >> 6;
        if ((t & 63) == 0) { ss[wv] = s; ssq[wv] = sq; }
        __syncthreads();
        s  = ss[0] + ss[1] + ss[2];
        sq = ssq[0] + ssq[1] + ssq[2];
        const float mean = s * (1.0f / 768.0f);
        const float var  = sq * (1.0f / 768.0f) - mean * mean;
        const float rstd = rsqrtf(var + 1e-5f);
        const float4 gv = *(const float4*)(g + c);
        const float4 bv = *(const float4*)(bvec + c);
        short4b o;
        o[0] = f2bf((v.x - mean) * rstd * gv.x + bv.x);
        o[1] = f2bf((v.y - mean) * rstd * gv.y + bv.y);
        o[2] = f2bf((v.z - mean) * rstd * gv.z + bv.z);
        o[3] = f2bf((v.w - mean) * rstd * gv.w + bv.w);
        *(short4b*)(hnout + row * 768 + c) = o;
    }
}

// ---------------------------------------------------------------------------
__global__ __launch_bounds__(192)
void reducen_kernel(const short* __restrict__ part, int nsplit, long pstride,
                    short* __restrict__ out, int grps)
{
    const int blk = blockIdx.x;
    const int row = blk / grps, grp = blk - row * grps;
    const long base = (long)row * grps * 768 + grp * 768 + (threadIdx.x << 2);
    float4 v = {0.f, 0.f, 0.f, 0.f};
    for (int s = 0; s < nsplit; ++s) {
        const short4b p = *(const short4b*)(part + (long)s * pstride + base);
        v.x += bf2f(p[0]); v.y += bf2f(p[1]); v.z += bf2f(p[2]); v.w += bf2f(p[3]);
    }
    short4b o;
    o[0] = f2bf(v.x); o[1] = f2bf(v.y); o[2] = f2bf(v.z); o[3] = f2bf(v.w);
    *(short4b*)(out + base) = o;
}

// ---------------------------------------------------------------------------
__global__ __launch_bounds__(64)
void groupfc_kernel(const float* __restrict__ h, const float* __restrict__ dp,
                    const float* __restrict__ bias, float* __restrict__ out)
{
    const int bg = blockIdx.x;
    const int g = bg % 100;
    const int t = threadIdx.x;
    const float* hr = h + (long)bg * 768;
    const float* d = dp + (long)g * 7680;
    float acc[10];
    #pragma unroll
    for (int f = 0; f < 10; ++f) acc[f] = 0.0f;
    for (int k = t; k < 768; k += 64) {
        const float hv = hr[k];
        const float* dr = d + k * 10;
        #pragma unroll
        for (int f = 0; f < 10; ++f) acc[f] += hv * dr[f];
    }
    #pragma unroll
    for (int f = 0; f < 10; ++f) {
        #pragma unroll
        for (int off = 32; off; off >>= 1) acc[f] += __shfl_xor(acc[f], off);
    }
    if (t == 0) {
        const int b = bg / 100;
        #pragma unroll
        for (int f = 0; f < 10; ++f)
            out[(long)b * 1000 + g * 10 + f] = acc[f] + bias[g * 10 + f];
    }
}

// ---------------------------------------------------------------------------
extern "C" void kernel_launch(void* const* d_in, const int* in_sizes, int n_in,
                              void* d_out, int out_size, void* d_ws, size_t ws_size,
                              hipStream_t stream)
{
    const float* x       = (const float*)d_in[0];
    const float* W_embed = (const float*)d_in[1];
    const float* b_embed = (const float*)d_in[2];
    const float* qe      = (const float*)d_in[3];
    const float* ln1_g   = (const float*)d_in[4];
    const float* ln1_b   = (const float*)d_in[5];
    const float* Wq_s    = (const float*)d_in[6];
    const float* Wk_s    = (const float*)d_in[7];
    const float* Wv_s    = (const float*)d_in[8];
    const float* Wo_s    = (const float*)d_in[9];
    const float* bo_s    = (const float*)d_in[10];
    const float* ln2_g   = (const float*)d_in[11];
    const float* ln2_b   = (const float*)d_in[12];
    const float* Wq_c    = (const float*)d_in[13];
    const float* Wk_c    = (const float*)d_in[14];
    const float* Wv_c    = (const float*)d_in[15];
    const float* Wo_c    = (const float*)d_in[16];
    const float* bo_c    = (const float*)d_in[17];
    const float* ln3_g   = (const float*)d_in[18];
    const float* ln3_b   = (const float*)d_in[19];
    const float* W1      = (const float*)d_in[20];
    const float* b1      = (const float*)d_in[21];
    const float* W2      = (const float*)d_in[22];
    const float* b2      = (const float*)d_in[23];
    const float* dpool   = (const float*)d_in[24];
    const float* dbias   = (const float*)d_in[25];

    char* base = (char*)d_ws;
    size_t off = 0;
    auto alloc = [&](size_t bytes) -> void* {
        void* p = base + off;
        off += (bytes + 255) & ~(size_t)255;
        return p;
    };
    short* ek    = (short*)alloc(12544L * 768 * 2);      // emb bf16 [12544][768]
    short* ekT   = (short*)alloc(64L * 768 * 256 * 2);   // emb^T [b][768][256] zero-pad
    short* big   = (short*)alloc(6400L * 6144 * 2);      // xT, then ctx_c
    char*  shr   = (char*) alloc(4L * 6400 * 768 * 4);   // prep casts / partials
    float* h2    = (float*)alloc(6400L * 768 * 4);       // residual stream (b-dep)
    short* hn3   = (short*)alloc(6400L * 768 * 2);
    short* t1    = (short*)alloc(6400L * 2048 * 2);
    short* WembT = (short*)alloc(768L * 2048 * 2);
    short* W1T   = (short*)alloc(2048L * 768 * 2);
    short* W2T   = (short*)alloc(768L * 2048 * 2);
    short* WqkTc = (short*)alloc(6144L * 768 * 2);       // [h][768][768] planes
    short* WvoTc = (short*)alloc(768L * 6144 * 2);
    short* WqsT  = (short*)alloc(6144L * 768 * 2);       // consecutive: WqsT/WksT/WvsT
    short* WksT  = (short*)alloc(6144L * 768 * 2);
    short* WvsT  = (short*)alloc(6144L * 768 * 2);
    short* WosT  = (short*)alloc(768L * 6144 * 2);
    short* hn1   = (short*)alloc(128L * 768 * 2);        // pad rows stale (finite)
    short* q_s   = (short*)alloc(128L * 6144 * 2);       // consecutive: q_s/k_s/v_s
    short* k_s   = (short*)alloc(128L * 6144 * 2);
    short* v_s   = (short*)alloc(128L * 6144 * 2);
    short* ctx_s = (short*)alloc(128L * 6144 * 2);
    short* v_sT  = (short*)alloc(6144L * 128 * 2);       // zero-pad cols >= 100
    short* qt_c  = (short*)alloc(128L * 6144 * 2);
    short* qtP   = (short*)alloc(4L * 100 * 6144 * 2);   // qt split-K partials bf16
    float* partS = (float*)alloc(8L * 100 * 768 * 4);
    float* h1    = (float*)alloc(128L * 768 * 4);
    short* hn2   = (short*)alloc(128L * 768 * 2);
    (void)ws_size; (void)in_sizes; (void)n_in; (void)out_size;

    // shr aliases (phase-disjoint): prep casts, then bf16 split-K planes
    short* CQ    = (short*)shr;
    short* CK    = CQ + 4718592L;
    short* CV    = CK + 4718592L;
    short* WoTc  = CV + 4718592L;
    short* partCb = (short*)shr;                         // [8][6400][768] bf16

    const float scale = 0.03608439182435161f;  // 768^-0.5

    // ================= merged prep (8 transposes + 3 casts + x + LN1) ======
    short* xT = big;  // [12544][2048] bf16
    prep_kernel<<<dim3(29028), 256, 0, stream>>>(
        W_embed, W1, W2, Wq_s, Wk_s, Wv_s, Wo_s, Wo_c,
        Wq_c, Wk_c, Wv_c, x, qe, ln1_g, ln1_b,
        WembT, W1T, W2T, WqsT, WksT, WvsT, WosT, WoTc,
        CQ, CK, CV, xT, hn1);

    // ---- combined cross weights (bf16 fast path) ----
    gemm_kernel<0, true, 128><<<dim3(6, 6, 8), 256, 0, stream>>>(
        CK, CQ, nullptr, nullptr, 1, WqkTc,
        768, 768, 768, 768, 768, 6144, 6144, 768, 8,
        0L, 768L, 0L, 768L, 0L, 589824L, 1.0f);
    gemm_kernel<0, true, 128><<<dim3(6, 6, 8), 256, 0, stream>>>(
        WoTc, CV, nullptr, nullptr, 1, WvoTc,
        768, 768, 768, 768, 768, 6144, 6144, 6144, 8,
        0L, 768L, 0L, 768L, 0L, 768L, 1.0f);

    // ================= embed =================
    gemm_kernel<1, true, 64><<<dim3(6, 196, 1), 256, 0, stream>>>(
        xT, WembT, b_embed, nullptr, 1, ek,
        12544, 768, 2048, 12544, 768, 2048, 2048, 768, 1,
        0L, 0L, 0L, 0L, 0L, 0L, 1.0f);
    transpose_kernel<false><<<dim3(12, 4, 64), 256, 0, stream>>>(ek, ekT, 196, 768, 256);

    // ================= self-attention (batch-invariant, 100 rows) ==========
    gemm_kernel<0, true, 128><<<dim3(48, 1, 3), 256, 0, stream>>>(
        hn1, WqsT, nullptr, nullptr, 1, q_s,
        100, 6144, 768, 128, 6144, 768, 768, 6144, 1,
        0L, 0L, 4718592L, 0L, 786432L, 0L, 1.0f);
    transpose_kernel<false><<<dim3(96, 2, 1), 256, 0, stream>>>(v_s, v_sT, 100, 6144, 128);
    attn_kernel<8, 2><<<dim3(8, 6, 1), 256, 0, stream>>>(
        q_s, k_s, v_sT, ctx_s,
        100, 8, 6144, 6144, 128, 6144,
        768, 768, 0L, 0L, 0L, scale);
    gemm_kernel<0, false, 128><<<dim3(6, 1, 8), 256, 0, stream>>>(
        ctx_s, WosT, nullptr, nullptr, 1, partS,
        100, 768, 768, 128, 768, 6144, 6144, 768, 8,
        0L, 768L, 0L, 768L, 0L, 76800L, 1.0f);
    reduce_kernel<true, false><<<dim3(100), 192, 0, stream>>>(
        partS, 8, 76800L, qe, 100, bo_s, ln2_g, ln2_b, h1, hn2);

    // ================= cross-attention =================
    gemm_kernel<0, true, 128><<<dim3(48, 1, 4), 256, 0, stream>>>(
        hn2, WqkTc, nullptr, nullptr, 1, qtP,
        100, 6144, 192, 128, 6144, 768, 768, 6144, 4,
        0L, 192L, 0L, 192L, 0L, 614400L, 1.0f);
    reducen_kernel<<<dim3(800), 192, 0, stream>>>(qtP, 4, 614400L, qt_c, 8);
    attn8_kernel<14><<<dim3(512), 512, 0, stream>>>(
        qt_c, ek, ekT, big,
        196, 6144, 768, 256, 6144,
        150528L, 196608L, 614400L, scale);
    gemm_kernel<0, true, 128><<<dim3(6, 50, 8), 256, 0, stream>>>(
        big, WvoTc, nullptr, nullptr, 1, partCb,
        6400, 768, 768, 6400, 768, 6144, 6144, 768, 8,
        0L, 768L, 0L, 768L, 0L, 4915200L, 1.0f);
    reduce_kernel<true, true><<<dim3(6400), 192, 0, stream>>>(
        partCb, 8, 4915200L, h1, 100, bo_c, ln3_g, ln3_b, h2, hn3);

    // ================= MLP =================
    gemm_kernel<2, true, 64><<<dim3(16, 100, 1), 256, 0, stream>>>(
        hn3, W1T, b1, nullptr, 1, t1,
        6400, 2048, 768, 6400, 2048, 768, 768, 2048, 1, 0,0,0,0,0,0, 1.0f);
    gemm_kernel<0, true, 128><<<dim3(6, 50, 4), 256, 0, stream>>>(
        t1, W2T, nullptr, nullptr, 1, partCb,
        6400, 768, 512, 6400, 768, 2048, 2048, 768, 4,
        0L, 512L, 0L, 512L, 0L, 4915200L, 1.0f);
    reduce_kernel<false, true><<<dim3(6400), 192, 0, stream>>>(
        partCb, 4, 4915200L, h2, 6400, b2, nullptr, nullptr, h2, nullptr);

    // ================= GroupFC =================
    groupfc_kernel<<<dim3(6400), 64, 0, stream>>>(h2, dpool, dbias, (float*)d_out);
}